// Round 9
// baseline (1058.432 us; speedup 1.0000x reference)
//
#include <hip/hip_runtime.h>
#include <hip/hip_bf16.h>
#include <math.h>

// ============================================================================
// MinimalNetwork, round 9: kill the scratch spill for real.
// Rounds 4-8's ~670 MB phantom WRITE = acc[8][9] (72 live floats/thread across
// 19 barriered phases) spilling to scratch. Fix: role r owns output rows
// u in {2r, 2r+1}; cross-phase accumulator is acc[2][9] = 18 floats, all
// compile-time indexed. tmp computed for all 8 v per thread (two groups of 4,
// phase-local). No merge shuffles; epilogue writes role-owned rows directly.
// sRt pitch 67 (role stride 16*67 = 16 mod 32 -> 2-way = free).
// ============================================================================

#define FEATD 72
#define NCOL 1216
#define SWISH_SCALE 1.679177f

typedef __attribute__((ext_vector_type(8))) short bf16x8;
typedef __attribute__((ext_vector_type(4))) float f32x4;

// ---- 19 (lo,li,lf) chunks; CB_OFF = offsets into the C3 coefficient pool ----
constexpr int NCOMBO = 19;
constexpr int CB_LO[NCOMBO] = {0,0,0,1,1,1,1,1,1,1,2,2,2,2,2,2,2,2,2};
constexpr int CB_LI[NCOMBO] = {0,1,2,0,1,1,1,2,2,2,0,1,1,1,2,2,2,2,2};
constexpr int CB_LF[NCOMBO] = {0,1,2,1,0,1,2,1,2,3,2,1,2,3,0,1,2,3,4};
constexpr int CB_OFF[NCOMBO] = {0,1,10,35,44,53,80,125,170,245,350,375,420,495,600,625,700,825,1000};
constexpr int CB_SZ[NCOMBO]  = {1,9,25,9,9,27,45,45,75,105,25,45,75,105,25,75,125,175,225};
constexpr int C3TOT = 1225;

constexpr int C3OFFT[3][3][5] = {
  { {0,-1,-1,-1,-1}, {-1,1,-1,-1,-1}, {-1,-1,10,-1,-1} },
  { {-1,35,-1,-1,-1}, {44,53,80,-1,-1}, {-1,125,170,245,-1} },
  { {-1,-1,350,-1,-1}, {-1,375,420,495,-1}, {600,625,700,825,1000} }
};
constexpr int ROFFT[3][3] = {{0,64,128},{192,256,448},{640,704,896}};
constexpr int FOFFT[3]   = {0,8,32};

__device__ const double d_fact[11] = {1.,1.,2.,6.,24.,120.,720.,5040.,40320.,362880.,3628800.};

// ---------------------------------------------------------------------------
// Wigner 3j (complex basis, Racah) in double precision + real change of basis
// ---------------------------------------------------------------------------
__device__ double w3j_entry(int j1,int j2,int j3,int m1,int m2,int m3){
  if (m1+m2+m3 != 0) return 0.0;
  int dj = j1-j2; if (dj<0) dj=-dj;
  if (j3 < dj || j3 > j1+j2) return 0.0;
  int t1 = j2 - m1 - j3, t2 = j1 + m2 - j3;
  int kmin = 0; if (t1>kmin) kmin=t1; if (t2>kmin) kmin=t2;
  int kmax = j1+j2-j3; if (j1-m1<kmax) kmax=j1-m1; if (j2+m2<kmax) kmax=j2+m2;
  double s = 0.0;
  for (int k=kmin;k<=kmax;++k){
    double den = d_fact[k]*d_fact[k-t1]*d_fact[k-t2]*d_fact[j1+j2-j3-k]
               * d_fact[j1-m1-k]*d_fact[j2+m2-k];
    s += ((k&1)? -1.0:1.0)/den;
  }
  double pref = sqrt(d_fact[j1+j2-j3]*d_fact[j1-j2+j3]*d_fact[-j1+j2+j3]/d_fact[j1+j2+j3+1]
               * d_fact[j1+m1]*d_fact[j1-m1]*d_fact[j2+m2]*d_fact[j2-m2]
               * d_fact[j3+m3]*d_fact[j3-m3]);
  int ex = j1-j2-m3;
  if (ex & 1) pref = -pref;
  return pref*s;
}

__device__ void cob(int l, int r, int c, double& re, double& im){
  re = 0.0; im = 0.0;
  int mr = r - l, mc = c - l;
  const double s = 0.70710678118654752440;
  if (mr == 0) { if (mc == 0) re = 1.0; return; }
  if (mr > 0) {
    if (mc == mr)       re = (mr & 1) ? -s : s;
    else if (mc == -mr) re = s;
  } else {
    int m = -mr;
    if (mc == -m)      im = s;
    else if (mc == m)  im = (m & 1) ? s : -s;
  }
}

__global__ void c3_build_kernel(double* __restrict__ Tre, double* __restrict__ Tim){
  int idx = blockIdx.x*64 + threadIdx.x;
  if (idx >= C3TOT) return;
  int c = 0;
  while (c+1 < NCOMBO && idx >= CB_OFF[c+1]) ++c;
  int lo = CB_LO[c], li = CB_LI[c], lf = CB_LF[c];
  int n2 = 2*li+1, n3 = 2*lf+1;
  int loc = idx - CB_OFF[c];
  int a = loc/(n2*n3), b = (loc/n3)%n2, g = loc%n3;
  double sre=0.0, sim=0.0;
  for (int m1=-lo; m1<=lo; ++m1){
    for (int m2=-li; m2<=li; ++m2){
      int m3 = -m1-m2;
      if (m3 < -lf || m3 > lf) continue;
      double w = w3j_entry(lo,li,lf,m1,m2,m3);
      if (w == 0.0) continue;
      double r1,i1,r2,i2,r3,i3;
      cob(lo, a, m1+lo, r1,i1);
      cob(li, b, m2+li, r2,i2);
      cob(lf, g, m3+lf, r3,i3);
      double rr = r1*r2 - i1*i2, ri = r1*i2 + i1*r2;
      double fr = rr*r3 - ri*i3, fi = rr*i3 + ri*r3;
      sre += fr*w; sim += fi*w;
    }
  }
  Tre[idx] = sre; Tim[idx] = sim;
}

__global__ void c3_norm_kernel(const double* __restrict__ Tre, const double* __restrict__ Tim,
                               float* __restrict__ C3f){
  int c = blockIdx.x;
  int off = CB_OFF[c], sz = CB_SZ[c];
  int t = threadIdx.x;
  double sre=0.0, sim=0.0;
  for (int p=t; p<sz; p+=64){ double x=Tre[off+p], y=Tim[off+p]; sre+=x*x; sim+=y*y; }
  for (int m=1; m<64; m<<=1){ sre += __shfl_xor(sre, m, 64); sim += __shfl_xor(sim, m, 64); }
  bool useRe = (sre >= sim);
  double n = sqrt(useRe ? sre : sim);
  double inv = (n > 0.0) ? 1.0/n : 1.0;
  for (int p=t; p<sz; p+=64){
    double v = useRe ? Tre[off+p] : Tim[off+p];
    C3f[off+p] = (float)(v*inv);
  }
}

// ---------------------------------------------------------------------------
// W3t[c'][k], c' chunk-major: c' = chunk*64 + uv maps to original column
// ROFFT[lo][li] + uv*nlf + fi. 0.1 scale folded. Pitch 136, pad k>=100 = 0.
// ---------------------------------------------------------------------------
__global__ __launch_bounds__(256) void prep_w3t_kernel(const float* __restrict__ W3,
                                                       __hip_bfloat16* __restrict__ W3t){
  int idx = blockIdx.x*256 + threadIdx.x;
  if (idx >= 1216*136) return;
  int cp = idx/136, k = idx%136;
  int chunk = cp>>6, uv = cp&63;
  int lo = CB_LO[chunk], li = CB_LI[chunk], lf = CB_LF[chunk];
  int lmin = lo<li ? lo : li;
  int nlf = 2*lmin+1;
  int fi = lf - (lo>li ? lo-li : li-lo);
  int c = ROFFT[lo][li] + uv*nlf + fi;
  float v = (k < 100) ? 0.1f*W3[(size_t)k*NCOL + c] : 0.f;
  W3t[idx] = __float2bfloat16(v);
}

// ---------------------------------------------------------------------------
// Radial hidden chain -> h_bf[e][136] bf16; layer3 staged in LDS, coalesced out
// ---------------------------------------------------------------------------
__device__ __forceinline__ float swishf(float s){
  return SWISH_SCALE * s / (1.f + __expf(-s));
}

__global__ __launch_bounds__(256) void radial_hidden_kernel(
    const float* __restrict__ radii,
    const float* __restrict__ W0, const float* __restrict__ W1, const float* __restrict__ W2,
    __hip_bfloat16* __restrict__ h_bf, int E)
{
  __shared__ float sW[10000];
  __shared__ __align__(16) float sX[6400];   // [er][k], pitch 100; reused as bf16 staging
  __shared__ float sY[6400];
  __shared__ float sbas[640];
  const int t = threadIdx.x;
  const int et0 = blockIdx.x*64;

  for (int p=t; p<640; p+=256){
    int er = p/10, k = p%10;
    int eg = et0 + er;
    float r = (eg < E) ? radii[eg] : 0.f;
    float c = 0.7f + (2.5f/9.0f)*(float)k;
    float d = (r - c) * (9.0f/2.5f);
    sbas[p] = __expf(-d*d);
  }
  for (int p=t; p<1000; p+=256) sW[p] = W0[p]*0.3162277660168379f; // 1/sqrt(10)
  __syncthreads();
  for (int p=t; p<6400; p+=256){
    int er = p/100, o = p%100;
    float s = 0.f;
    #pragma unroll
    for (int k=0;k<10;++k) s += sbas[er*10+k]*sW[k*100+o];
    sX[p] = swishf(s);
  }
  __syncthreads();
  for (int p=t; p<10000; p+=256) sW[p] = W1[p]*0.1f;
  __syncthreads();
  for (int q=t; q<400; q+=256){
    int erb = (q/25)*4, ob = (q%25)*4;
    float acc[4][4] = {};
    for (int k=0;k<100;++k){
      float4 w = *(const float4*)&sW[k*100+ob];
      #pragma unroll
      for (int i=0;i<4;++i){
        float a = sX[(erb+i)*100+k];
        acc[i][0]+=a*w.x; acc[i][1]+=a*w.y; acc[i][2]+=a*w.z; acc[i][3]+=a*w.w;
      }
    }
    #pragma unroll
    for (int i=0;i<4;++i){
      float4 v = make_float4(swishf(acc[i][0]),swishf(acc[i][1]),swishf(acc[i][2]),swishf(acc[i][3]));
      *(float4*)&sY[(erb+i)*100+ob] = v;
    }
  }
  __syncthreads();   // layer2 done reading sX -> sX reusable as staging
  for (int p=t; p<10000; p+=256) sW[p] = W2[p]*0.1f;
  __syncthreads();

  // layer 3: compute into LDS staging (bf16 [64][136]), then coalesced copy-out
  __hip_bfloat16* sHB = (__hip_bfloat16*)sX;   // 17408 B <= 25600 B
  for (int p=t; p<64*36; p+=256){
    int er = p/36, k = 100 + p%36;
    sHB[er*136 + k] = __float2bfloat16(0.f);
  }
  for (int q=t; q<400; q+=256){
    int erb = (q/25)*4, ob = (q%25)*4;
    float acc[4][4] = {};
    for (int k=0;k<100;++k){
      float4 w = *(const float4*)&sW[k*100+ob];
      #pragma unroll
      for (int i=0;i<4;++i){
        float a = sY[(erb+i)*100+k];
        acc[i][0]+=a*w.x; acc[i][1]+=a*w.y; acc[i][2]+=a*w.z; acc[i][3]+=a*w.w;
      }
    }
    #pragma unroll
    for (int i=0;i<4;++i){
      __hip_bfloat16 hv[4];
      #pragma unroll
      for (int j=0;j<4;++j) hv[j] = __float2bfloat16(swishf(acc[i][j]));
      *(short4*)&sHB[(erb+i)*136 + ob] = *(short4*)hv;
    }
  }
  __syncthreads();
  {
    const float4* sm = (const float4*)sHB;
    float4* gm = (float4*)(h_bf + (size_t)et0*136);
    for (int p=t; p<1088; p+=256) gm[p] = sm[p];
  }
}

// ---------------------------------------------------------------------------
// CSR of edges by target node
// ---------------------------------------------------------------------------
__global__ __launch_bounds__(256) void hist_kernel(const int* __restrict__ ei,
                                                   int* __restrict__ deg, int E){
  int e = blockIdx.x*256 + threadIdx.x;
  if (e < E) atomicAdd(&deg[ei[E+e]], 1);
}

__global__ __launch_bounds__(256) void scan_kernel(const int* __restrict__ deg,
                                                   int* __restrict__ off,
                                                   int* __restrict__ cursor, int N, int E){
  __shared__ int part[256], spref[256];
  const int t = threadIdx.x;
  const int CH = (N + 255)/256;
  int lo = t*CH, hi = lo+CH < N ? lo+CH : N;
  int s = 0;
  for (int n=lo; n<hi; ++n) s += deg[n];
  part[t] = s;
  __syncthreads();
  if (t == 0){
    int run = 0;
    for (int i=0;i<256;++i){ spref[i] = run; run += part[i]; }
  }
  __syncthreads();
  int run = spref[t];
  for (int n=lo; n<hi; ++n){ off[n] = run; cursor[n] = run; run += deg[n]; }
  if (t == 255) off[N] = E;
}

__global__ __launch_bounds__(256) void fill_kernel(const int* __restrict__ ei,
                                                   int* __restrict__ cursor,
                                                   int* __restrict__ eid, int E){
  int e = blockIdx.x*256 + threadIdx.x;
  if (e < E){
    int idx = atomicAdd(&cursor[ei[E+e]], 1);
    eid[idx] = e;
  }
}

// ---------------------------------------------------------------------------
// Gather: one 64-lane wave per node; writes every output element exactly once.
// ---------------------------------------------------------------------------
__global__ __launch_bounds__(64) void gather_kernel(const float* __restrict__ msg,
                                                    const int* __restrict__ off,
                                                    const int* __restrict__ eid,
                                                    float* __restrict__ out, int N){
  const int n = blockIdx.x;
  const int t = threadIdx.x;
  const int s = off[n], e1 = off[n+1];
  float a0 = 0.f, a1 = 0.f;
  for (int i=s; i<e1; ++i){
    const float* m = msg + (size_t)eid[i]*FEATD;
    a0 += m[t];
    if (t < 8) a1 += m[64+t];
  }
  out[(size_t)n*FEATD + t] = a0;
  if (t < 8) out[(size_t)n*FEATD + 64 + t] = a1;
}

// ---------------------------------------------------------------------------
// Fused GEMM+TP. 256 threads = 4 waves; 64 edges/block; 4 roles/edge.
// Role r owns output rows u in {2r,2r+1}: cross-phase acc = 18 floats/thread.
// ---------------------------------------------------------------------------
#define RTP 67   // sRt pitch: consume role stride 16*67 = 1072 ≡ 16 mod 32 -> 2-way

constexpr int OF_W3A = 0;         // 64*136 bf16 = 17408
constexpr int OF_W3B = 17408;     // 64*136 bf16 = 17408
constexpr int OF_RT  = 34816;     // 64*67 f32   = 17152
constexpr int OF_F   = 51968;     // 64*74 bf16  = 9472
constexpr int OF_RSH = 61440;     // 64*26 f32   = 6656
constexpr int OF_KV  = 68096;     // 64*26 f32   = 6656
constexpr int OF_C3  = 74752;     // 1228 f32    = 4912
constexpr int OF_SRC = 79664;     // 64 int      = 256
constexpr int SMEM_SZ = 79920;

template<int LO,int LI,int LF, bool PF>
__device__ __forceinline__ void phase(
    int nextChunk, const __hip_bfloat16* __restrict__ W3t,
    const bf16x8 (&hf)[4],
    __hip_bfloat16* sW3src, __hip_bfloat16* sW3dst, float* sRt,
    __hip_bfloat16* sF, float* sRsh, float* sKV, const float* sC3,
    float (&acc)[2][9], int t)
{
  constexpr int NO = 2*LO+1, NI = 2*LI+1, NF = 2*LF+1;
  constexpr int C3B = C3OFFT[LO][LI][LF];
  constexpr int FO  = FOFFT[LI];
  constexpr int AO  = (LO==0) ? 0 : (LO==1) ? 1 : 4;

  // ---- 1. prefetch next chunk's 64 W3t rows into the other buffer ----
  if (PF){
    const float4* g = (const float4*)(W3t + (size_t)nextChunk*64*136);
    float4* s = (float4*)sW3dst;
    for (int p=t; p<1088; p+=256) s[p] = g[p];
  }
  // ---- 2. cooperative kv[e][o*NI+mi] = sum_mf C3 * y ----
  {
    const int le = t & 63, wv = t >> 6;
    float y[NF];
    #pragma unroll
    for (int mf=0; mf<NF; ++mf) y[mf] = sRsh[le*26 + LF*LF + mf];
    for (int it = wv; it < NO*NI; it += 4){
      float s = 0.f;
      #pragma unroll
      for (int mf=0; mf<NF; ++mf) s += sC3[C3B + it*NF + mf] * y[mf];
      sKV[le*26 + it] = s;
    }
  }
  // ---- 3. MFMA: Rt_chunk[c=uv][e], 64x64, K=128; B-operand from registers ----
  {
    const int lane = t & 63, wv = t >> 6;
    const int lr = lane & 15, lq = lane >> 4;
    f32x4 a4[4] = {};
    #pragma unroll
    for (int ks=0; ks<4; ++ks){
      #pragma unroll
      for (int ct=0; ct<4; ++ct){
        bf16x8 a = *(const bf16x8*)&sW3src[(ct*16+lr)*136 + ks*32 + lq*8];
        a4[ct] = __builtin_amdgcn_mfma_f32_16x16x32_bf16(a, hf[ks], a4[ct], 0, 0, 0);
      }
    }
    #pragma unroll
    for (int ct=0; ct<4; ++ct)
      #pragma unroll
      for (int r=0; r<4; ++r)
        sRt[(ct*16 + lq*4 + r)*RTP + wv*16 + lr] = a4[ct][r];
  }
  __syncthreads();   // sRt + sKV + prefetched W3 visible

  // ---- 4. TP consume: role owns u in {2*role, 2*role+1}; all 8 v per thread
  //         (two groups of 4 to cap phase-local register pressure) ----
  {
    const int e = t >> 2, role = t & 3;
    #pragma unroll
    for (int vg=0; vg<2; ++vg){
      float Fv[4][NI];
      #pragma unroll
      for (int v=0; v<4; ++v)
        #pragma unroll
        for (int mi=0; mi<NI; ++mi)
          Fv[v][mi] = __bfloat162float(sF[e*74 + FO + (vg*4+v)*NI + mi]);
      float tmp[4][NO];
      #pragma unroll
      for (int v=0; v<4; ++v)
        #pragma unroll
        for (int o=0; o<NO; ++o) tmp[v][o] = 0.f;
      #pragma unroll
      for (int o=0; o<NO; ++o)
        #pragma unroll
        for (int mi=0; mi<NI; ++mi){
          float kvv = sKV[e*26 + o*NI + mi];
          #pragma unroll
          for (int v=0; v<4; ++v) tmp[v][o] += kvv * Fv[v][mi];
        }
      #pragma unroll
      for (int du=0; du<2; ++du){
        const int u = role*2 + du;           // runtime only in LDS address
        #pragma unroll
        for (int v=0; v<4; ++v){
          float r = sRt[(u*8 + vg*4 + v)*RTP + e];
          #pragma unroll
          for (int o=0; o<NO; ++o) acc[du][AO+o] += r * tmp[v][o];
        }
      }
    }
  }
  __syncthreads();   // consume done: sRt/sKV free; src buffer free for prefetch
}

__global__ __launch_bounds__(256,2) void fused_kernel(
    const float* __restrict__ feats, const int* __restrict__ ei,
    const float* __restrict__ rsh, const __hip_bfloat16* __restrict__ h_bf,
    const __hip_bfloat16* __restrict__ W3t, const float* __restrict__ C3g,
    float* __restrict__ msg, int E)
{
  __shared__ __align__(16) char smem[SMEM_SZ];
  __hip_bfloat16* sW3A = (__hip_bfloat16*)(smem + OF_W3A);
  __hip_bfloat16* sW3B = (__hip_bfloat16*)(smem + OF_W3B);
  float* sRt  = (float*)(smem + OF_RT);
  __hip_bfloat16* sF = (__hip_bfloat16*)(smem + OF_F);
  float* sRsh = (float*)(smem + OF_RSH);
  float* sKV  = (float*)(smem + OF_KV);
  float* sC3  = (float*)(smem + OF_C3);
  int*   sSrc = (int*)(smem + OF_SRC);

  const int t = threadIdx.x;
  const int eb = blockIdx.x*64;

  // ---- h fragments into registers (B-operand, fixed across all 19 phases) ----
  bf16x8 hf[4];
  {
    const int lane = t & 63, wv = t >> 6;
    const int lr = lane & 15, lq = lane >> 4;
    const __hip_bfloat16* hrow = h_bf + (size_t)(eb + wv*16 + lr)*136;
    #pragma unroll
    for (int ks=0; ks<4; ++ks)
      hf[ks] = *(const bf16x8*)&hrow[ks*32 + lq*8];
  }
  // ---- prologue staging ----
  {
    const float4* g = (const float4*)W3t;   // chunk 0
    float4* s = (float4*)sW3A;
    for (int p=t; p<1088; p+=256) s[p] = g[p];
  }
  for (int p=t; p<64; p+=256){
    int e = eb + p;
    sSrc[p] = (e < E) ? ei[e] : 0;
  }
  for (int p=t; p<1600; p+=256){
    int el = p/25, j = p%25;
    int e = eb + el;
    sRsh[el*26 + j] = (e < E) ? rsh[(size_t)e*25 + j] : 0.f;
  }
  for (int p=t; p<C3TOT; p+=256) sC3[p] = C3g[p];
  __syncthreads();
  for (int p=t; p<64*72; p+=256){
    int el = p/72, j = p%72;
    sF[el*74 + j] = __float2bfloat16(feats[(size_t)sSrc[el]*72 + j]);
  }
  // (sF consumed only after phase 0's mid-phase barrier — no extra sync needed)

  float acc[2][9];
  #pragma unroll
  for (int du=0; du<2; ++du)
    #pragma unroll
    for (int j=0; j<9; ++j) acc[du][j] = 0.f;

  // ---- 19 phases, alternating W3 buffers (chunk k reads buf[k&1]) ----
  phase<0,0,0,true >( 1, W3t, hf, sW3A, sW3B, sRt, sF, sRsh, sKV, sC3, acc, t);
  phase<0,1,1,true >( 2, W3t, hf, sW3B, sW3A, sRt, sF, sRsh, sKV, sC3, acc, t);
  phase<0,2,2,true >( 3, W3t, hf, sW3A, sW3B, sRt, sF, sRsh, sKV, sC3, acc, t);
  phase<1,0,1,true >( 4, W3t, hf, sW3B, sW3A, sRt, sF, sRsh, sKV, sC3, acc, t);
  phase<1,1,0,true >( 5, W3t, hf, sW3A, sW3B, sRt, sF, sRsh, sKV, sC3, acc, t);
  phase<1,1,1,true >( 6, W3t, hf, sW3B, sW3A, sRt, sF, sRsh, sKV, sC3, acc, t);
  phase<1,1,2,true >( 7, W3t, hf, sW3A, sW3B, sRt, sF, sRsh, sKV, sC3, acc, t);
  phase<1,2,1,true >( 8, W3t, hf, sW3B, sW3A, sRt, sF, sRsh, sKV, sC3, acc, t);
  phase<1,2,2,true >( 9, W3t, hf, sW3A, sW3B, sRt, sF, sRsh, sKV, sC3, acc, t);
  phase<1,2,3,true >(10, W3t, hf, sW3B, sW3A, sRt, sF, sRsh, sKV, sC3, acc, t);
  phase<2,0,2,true >(11, W3t, hf, sW3A, sW3B, sRt, sF, sRsh, sKV, sC3, acc, t);
  phase<2,1,1,true >(12, W3t, hf, sW3B, sW3A, sRt, sF, sRsh, sKV, sC3, acc, t);
  phase<2,1,2,true >(13, W3t, hf, sW3A, sW3B, sRt, sF, sRsh, sKV, sC3, acc, t);
  phase<2,1,3,true >(14, W3t, hf, sW3B, sW3A, sRt, sF, sRsh, sKV, sC3, acc, t);
  phase<2,2,0,true >(15, W3t, hf, sW3A, sW3B, sRt, sF, sRsh, sKV, sC3, acc, t);
  phase<2,2,1,true >(16, W3t, hf, sW3B, sW3A, sRt, sF, sRsh, sKV, sC3, acc, t);
  phase<2,2,2,true >(17, W3t, hf, sW3A, sW3B, sRt, sF, sRsh, sKV, sC3, acc, t);
  phase<2,2,3,true >(18, W3t, hf, sW3B, sW3A, sRt, sF, sRsh, sKV, sC3, acc, t);
  phase<2,2,4,false>(19, W3t, hf, sW3A, sW3B, sRt, sF, sRsh, sKV, sC3, acc, t);

  // ---- epilogue: role writes its own u-rows (register indices compile-time;
  //      runtime u only in LDS addresses), then coalesced float4 stream out ----
  float* sMsg = (float*)smem;    // 64*72 f32 = 18432 B over dead sW3A+sW3B
  {
    const int e = t >> 2, role = t & 3;
    float* dst = sMsg + e*72;
    #pragma unroll
    for (int du=0; du<2; ++du){
      const int u = role*2 + du;
      dst[u] = acc[du][0]*0.72360125f;                       // lo=0: sqrt(pi/6)
      #pragma unroll
      for (int o=0; o<3; ++o)
        dst[8 + u*3 + o] = acc[du][1+o]*0.8204867f;          // lo=1: sqrt(3pi/14)
      #pragma unroll
      for (int o=0; o<5; ++o)
        dst[32 + u*5 + o] = acc[du][4+o]*0.9341652f;         // lo=2: sqrt(5pi/18)
    }
  }
  __syncthreads();
  {
    const float4* sm = (const float4*)sMsg;
    float4* gm = (float4*)(msg + (size_t)eb*FEATD);
    for (int p=t; p<1152; p+=256) gm[p] = sm[p];
  }
}

// ---------------------------------------------------------------------------
extern "C" void kernel_launch(void* const* d_in, const int* in_sizes, int n_in,
                              void* d_out, int out_size, void* d_ws, size_t ws_size,
                              hipStream_t stream)
{
  const float* feats = (const float*)d_in[0];
  const int*   ei    = (const int*)d_in[1];
  const float* radii = (const float*)d_in[2];
  const float* rsh   = (const float*)d_in[3];
  const float* W0    = (const float*)d_in[4];
  const float* W1    = (const float*)d_in[5];
  const float* W2    = (const float*)d_in[6];
  const float* W3    = (const float*)d_in[7];
  float* out = (float*)d_out;
  const int E = in_sizes[2];
  const int N = in_sizes[0]/FEATD;

  const int EPAD = ((E + 63)/64)*64;
  const int NBLK = EPAD/64;

  char* ws = (char*)d_ws;
  size_t off_b = 0;
  float*  C3f = (float*)(ws + off_b);  off_b += 8192;
  double* Tre = (double*)(ws + off_b); off_b += 12288;
  double* Tim = (double*)(ws + off_b); off_b += 12288;          // 32768
  __hip_bfloat16* W3t  = (__hip_bfloat16*)(ws + off_b); off_b += 335872;  // 368640
  __hip_bfloat16* h_bf = (__hip_bfloat16*)(ws + off_b); off_b += (size_t)EPAD*272;
  float* msg = (float*)(ws + off_b);   off_b += (size_t)EPAD*FEATD*4;
  int* deg    = (int*)(ws + off_b);    off_b += (size_t)N*4;
  int* offv   = (int*)(ws + off_b);    off_b += (size_t)(N+1)*4;
  int* cursor = (int*)(ws + off_b);    off_b += (size_t)N*4;
  int* eid    = (int*)(ws + off_b);    off_b += (size_t)E*4;

  // constants / tables
  c3_build_kernel<<<dim3((C3TOT+63)/64), dim3(64), 0, stream>>>(Tre, Tim);
  c3_norm_kernel<<<dim3(NCOMBO), dim3(64), 0, stream>>>(Tre, Tim, C3f);
  prep_w3t_kernel<<<dim3((1216*136+255)/256), dim3(256), 0, stream>>>(W3, W3t);

  // CSR of edges by target
  hipMemsetAsync(deg, 0, (size_t)N*4, stream);
  hist_kernel<<<dim3((E+255)/256), dim3(256), 0, stream>>>(ei, deg, E);
  scan_kernel<<<dim3(1), dim3(256), 0, stream>>>(deg, offv, cursor, N, E);
  fill_kernel<<<dim3((E+255)/256), dim3(256), 0, stream>>>(ei, cursor, eid, E);

  // main pipeline
  radial_hidden_kernel<<<dim3(NBLK), dim3(256), 0, stream>>>(radii, W0, W1, W2, h_bf, E);
  fused_kernel<<<dim3(NBLK), dim3(256), 0, stream>>>(feats, ei, rsh, h_bf, W3t, C3f, msg, E);
  gather_kernel<<<dim3(N), dim3(64), 0, stream>>>(msg, offv, eid, out, N);
}

// Round 10
// 638.042 us; speedup vs baseline: 1.6589x; 1.6589x over previous
//
#include <hip/hip_runtime.h>
#include <hip/hip_bf16.h>
#include <math.h>

// ============================================================================
// MinimalNetwork, round 10: cross-phase accumulator moved to LDS.
// r4-r9's 660-1090 MB phantom HBM WRITE = per-phase scratch spill of the
// phase-local consume arrays + register accumulator held live across 19
// barriered phases. Fix: message accumulator lives in LDS (sAcc[64][72],
// msg-layout, role-disjoint RMW); registers carry only hf[4] across phases.
// Single-buffered W3 staging (dbuf measured neutral) to fit 2 blocks/CU.
// sRt pitch 67: u-ownership role stride 16*67 ≡ 16 mod 32 -> 2-way (free).
// ============================================================================

#define FEATD 72
#define NCOL 1216
#define SWISH_SCALE 1.679177f

typedef __attribute__((ext_vector_type(8))) short bf16x8;
typedef __attribute__((ext_vector_type(4))) float f32x4;

// ---- 19 (lo,li,lf) chunks; CB_OFF = offsets into the C3 coefficient pool ----
constexpr int NCOMBO = 19;
constexpr int CB_LO[NCOMBO] = {0,0,0,1,1,1,1,1,1,1,2,2,2,2,2,2,2,2,2};
constexpr int CB_LI[NCOMBO] = {0,1,2,0,1,1,1,2,2,2,0,1,1,1,2,2,2,2,2};
constexpr int CB_LF[NCOMBO] = {0,1,2,1,0,1,2,1,2,3,2,1,2,3,0,1,2,3,4};
constexpr int CB_OFF[NCOMBO] = {0,1,10,35,44,53,80,125,170,245,350,375,420,495,600,625,700,825,1000};
constexpr int CB_SZ[NCOMBO]  = {1,9,25,9,9,27,45,45,75,105,25,45,75,105,25,75,125,175,225};
constexpr int C3TOT = 1225;

constexpr int C3OFFT[3][3][5] = {
  { {0,-1,-1,-1,-1}, {-1,1,-1,-1,-1}, {-1,-1,10,-1,-1} },
  { {-1,35,-1,-1,-1}, {44,53,80,-1,-1}, {-1,125,170,245,-1} },
  { {-1,-1,350,-1,-1}, {-1,375,420,495,-1}, {600,625,700,825,1000} }
};
constexpr int ROFFT[3][3] = {{0,64,128},{192,256,448},{640,704,896}};
constexpr int FOFFT[3]   = {0,8,32};

__device__ const double d_fact[11] = {1.,1.,2.,6.,24.,120.,720.,5040.,40320.,362880.,3628800.};

// ---------------------------------------------------------------------------
// Wigner 3j (complex basis, Racah) in double precision + real change of basis
// ---------------------------------------------------------------------------
__device__ double w3j_entry(int j1,int j2,int j3,int m1,int m2,int m3){
  if (m1+m2+m3 != 0) return 0.0;
  int dj = j1-j2; if (dj<0) dj=-dj;
  if (j3 < dj || j3 > j1+j2) return 0.0;
  int t1 = j2 - m1 - j3, t2 = j1 + m2 - j3;
  int kmin = 0; if (t1>kmin) kmin=t1; if (t2>kmin) kmin=t2;
  int kmax = j1+j2-j3; if (j1-m1<kmax) kmax=j1-m1; if (j2+m2<kmax) kmax=j2+m2;
  double s = 0.0;
  for (int k=kmin;k<=kmax;++k){
    double den = d_fact[k]*d_fact[k-t1]*d_fact[k-t2]*d_fact[j1+j2-j3-k]
               * d_fact[j1-m1-k]*d_fact[j2+m2-k];
    s += ((k&1)? -1.0:1.0)/den;
  }
  double pref = sqrt(d_fact[j1+j2-j3]*d_fact[j1-j2+j3]*d_fact[-j1+j2+j3]/d_fact[j1+j2+j3+1]
               * d_fact[j1+m1]*d_fact[j1-m1]*d_fact[j2+m2]*d_fact[j2-m2]
               * d_fact[j3+m3]*d_fact[j3-m3]);
  int ex = j1-j2-m3;
  if (ex & 1) pref = -pref;
  return pref*s;
}

__device__ void cob(int l, int r, int c, double& re, double& im){
  re = 0.0; im = 0.0;
  int mr = r - l, mc = c - l;
  const double s = 0.70710678118654752440;
  if (mr == 0) { if (mc == 0) re = 1.0; return; }
  if (mr > 0) {
    if (mc == mr)       re = (mr & 1) ? -s : s;
    else if (mc == -mr) re = s;
  } else {
    int m = -mr;
    if (mc == -m)      im = s;
    else if (mc == m)  im = (m & 1) ? s : -s;
  }
}

__global__ void c3_build_kernel(double* __restrict__ Tre, double* __restrict__ Tim){
  int idx = blockIdx.x*64 + threadIdx.x;
  if (idx >= C3TOT) return;
  int c = 0;
  while (c+1 < NCOMBO && idx >= CB_OFF[c+1]) ++c;
  int lo = CB_LO[c], li = CB_LI[c], lf = CB_LF[c];
  int n2 = 2*li+1, n3 = 2*lf+1;
  int loc = idx - CB_OFF[c];
  int a = loc/(n2*n3), b = (loc/n3)%n2, g = loc%n3;
  double sre=0.0, sim=0.0;
  for (int m1=-lo; m1<=lo; ++m1){
    for (int m2=-li; m2<=li; ++m2){
      int m3 = -m1-m2;
      if (m3 < -lf || m3 > lf) continue;
      double w = w3j_entry(lo,li,lf,m1,m2,m3);
      if (w == 0.0) continue;
      double r1,i1,r2,i2,r3,i3;
      cob(lo, a, m1+lo, r1,i1);
      cob(li, b, m2+li, r2,i2);
      cob(lf, g, m3+lf, r3,i3);
      double rr = r1*r2 - i1*i2, ri = r1*i2 + i1*r2;
      double fr = rr*r3 - ri*i3, fi = rr*i3 + ri*r3;
      sre += fr*w; sim += fi*w;
    }
  }
  Tre[idx] = sre; Tim[idx] = sim;
}

__global__ void c3_norm_kernel(const double* __restrict__ Tre, const double* __restrict__ Tim,
                               float* __restrict__ C3f){
  int c = blockIdx.x;
  int off = CB_OFF[c], sz = CB_SZ[c];
  int t = threadIdx.x;
  double sre=0.0, sim=0.0;
  for (int p=t; p<sz; p+=64){ double x=Tre[off+p], y=Tim[off+p]; sre+=x*x; sim+=y*y; }
  for (int m=1; m<64; m<<=1){ sre += __shfl_xor(sre, m, 64); sim += __shfl_xor(sim, m, 64); }
  bool useRe = (sre >= sim);
  double n = sqrt(useRe ? sre : sim);
  double inv = (n > 0.0) ? 1.0/n : 1.0;
  for (int p=t; p<sz; p+=64){
    double v = useRe ? Tre[off+p] : Tim[off+p];
    C3f[off+p] = (float)(v*inv);
  }
}

// ---------------------------------------------------------------------------
// W3t[c'][k], c' chunk-major: c' = chunk*64 + uv maps to original column
// ROFFT[lo][li] + uv*nlf + fi. 0.1 scale folded. Pitch 136, pad k>=100 = 0.
// ---------------------------------------------------------------------------
__global__ __launch_bounds__(256) void prep_w3t_kernel(const float* __restrict__ W3,
                                                       __hip_bfloat16* __restrict__ W3t){
  int idx = blockIdx.x*256 + threadIdx.x;
  if (idx >= 1216*136) return;
  int cp = idx/136, k = idx%136;
  int chunk = cp>>6, uv = cp&63;
  int lo = CB_LO[chunk], li = CB_LI[chunk], lf = CB_LF[chunk];
  int lmin = lo<li ? lo : li;
  int nlf = 2*lmin+1;
  int fi = lf - (lo>li ? lo-li : li-lo);
  int c = ROFFT[lo][li] + uv*nlf + fi;
  float v = (k < 100) ? 0.1f*W3[(size_t)k*NCOL + c] : 0.f;
  W3t[idx] = __float2bfloat16(v);
}

// ---------------------------------------------------------------------------
// Radial hidden chain -> h_bf[e][136] bf16; layer3 staged in LDS, coalesced out
// ---------------------------------------------------------------------------
__device__ __forceinline__ float swishf(float s){
  return SWISH_SCALE * s / (1.f + __expf(-s));
}

__global__ __launch_bounds__(256) void radial_hidden_kernel(
    const float* __restrict__ radii,
    const float* __restrict__ W0, const float* __restrict__ W1, const float* __restrict__ W2,
    __hip_bfloat16* __restrict__ h_bf, int E)
{
  __shared__ float sW[10000];
  __shared__ __align__(16) float sX[6400];   // [er][k], pitch 100; reused as bf16 staging
  __shared__ float sY[6400];
  __shared__ float sbas[640];
  const int t = threadIdx.x;
  const int et0 = blockIdx.x*64;

  for (int p=t; p<640; p+=256){
    int er = p/10, k = p%10;
    int eg = et0 + er;
    float r = (eg < E) ? radii[eg] : 0.f;
    float c = 0.7f + (2.5f/9.0f)*(float)k;
    float d = (r - c) * (9.0f/2.5f);
    sbas[p] = __expf(-d*d);
  }
  for (int p=t; p<1000; p+=256) sW[p] = W0[p]*0.3162277660168379f; // 1/sqrt(10)
  __syncthreads();
  for (int p=t; p<6400; p+=256){
    int er = p/100, o = p%100;
    float s = 0.f;
    #pragma unroll
    for (int k=0;k<10;++k) s += sbas[er*10+k]*sW[k*100+o];
    sX[p] = swishf(s);
  }
  __syncthreads();
  for (int p=t; p<10000; p+=256) sW[p] = W1[p]*0.1f;
  __syncthreads();
  for (int q=t; q<400; q+=256){
    int erb = (q/25)*4, ob = (q%25)*4;
    float acc[4][4] = {};
    for (int k=0;k<100;++k){
      float4 w = *(const float4*)&sW[k*100+ob];
      #pragma unroll
      for (int i=0;i<4;++i){
        float a = sX[(erb+i)*100+k];
        acc[i][0]+=a*w.x; acc[i][1]+=a*w.y; acc[i][2]+=a*w.z; acc[i][3]+=a*w.w;
      }
    }
    #pragma unroll
    for (int i=0;i<4;++i){
      float4 v = make_float4(swishf(acc[i][0]),swishf(acc[i][1]),swishf(acc[i][2]),swishf(acc[i][3]));
      *(float4*)&sY[(erb+i)*100+ob] = v;
    }
  }
  __syncthreads();   // layer2 done reading sX -> sX reusable as staging
  for (int p=t; p<10000; p+=256) sW[p] = W2[p]*0.1f;
  __syncthreads();

  // layer 3: compute into LDS staging (bf16 [64][136]), then coalesced copy-out
  __hip_bfloat16* sHB = (__hip_bfloat16*)sX;   // 17408 B <= 25600 B
  for (int p=t; p<64*36; p+=256){
    int er = p/36, k = 100 + p%36;
    sHB[er*136 + k] = __float2bfloat16(0.f);
  }
  for (int q=t; q<400; q+=256){
    int erb = (q/25)*4, ob = (q%25)*4;
    float acc[4][4] = {};
    for (int k=0;k<100;++k){
      float4 w = *(const float4*)&sW[k*100+ob];
      #pragma unroll
      for (int i=0;i<4;++i){
        float a = sY[(erb+i)*100+k];
        acc[i][0]+=a*w.x; acc[i][1]+=a*w.y; acc[i][2]+=a*w.z; acc[i][3]+=a*w.w;
      }
    }
    #pragma unroll
    for (int i=0;i<4;++i){
      __hip_bfloat16 hv[4];
      #pragma unroll
      for (int j=0;j<4;++j) hv[j] = __float2bfloat16(swishf(acc[i][j]));
      *(short4*)&sHB[(erb+i)*136 + ob] = *(short4*)hv;
    }
  }
  __syncthreads();
  {
    const float4* sm = (const float4*)sHB;
    float4* gm = (float4*)(h_bf + (size_t)et0*136);
    for (int p=t; p<1088; p+=256) gm[p] = sm[p];
  }
}

// ---------------------------------------------------------------------------
// CSR of edges by target node
// ---------------------------------------------------------------------------
__global__ __launch_bounds__(256) void hist_kernel(const int* __restrict__ ei,
                                                   int* __restrict__ deg, int E){
  int e = blockIdx.x*256 + threadIdx.x;
  if (e < E) atomicAdd(&deg[ei[E+e]], 1);
}

__global__ __launch_bounds__(256) void scan_kernel(const int* __restrict__ deg,
                                                   int* __restrict__ off,
                                                   int* __restrict__ cursor, int N, int E){
  __shared__ int part[256], spref[256];
  const int t = threadIdx.x;
  const int CH = (N + 255)/256;
  int lo = t*CH, hi = lo+CH < N ? lo+CH : N;
  int s = 0;
  for (int n=lo; n<hi; ++n) s += deg[n];
  part[t] = s;
  __syncthreads();
  if (t == 0){
    int run = 0;
    for (int i=0;i<256;++i){ spref[i] = run; run += part[i]; }
  }
  __syncthreads();
  int run = spref[t];
  for (int n=lo; n<hi; ++n){ off[n] = run; cursor[n] = run; run += deg[n]; }
  if (t == 255) off[N] = E;
}

__global__ __launch_bounds__(256) void fill_kernel(const int* __restrict__ ei,
                                                   int* __restrict__ cursor,
                                                   int* __restrict__ eid, int E){
  int e = blockIdx.x*256 + threadIdx.x;
  if (e < E){
    int idx = atomicAdd(&cursor[ei[E+e]], 1);
    eid[idx] = e;
  }
}

// ---------------------------------------------------------------------------
// Gather: one 64-lane wave per node; writes every output element exactly once.
// ---------------------------------------------------------------------------
__global__ __launch_bounds__(64) void gather_kernel(const float* __restrict__ msg,
                                                    const int* __restrict__ off,
                                                    const int* __restrict__ eid,
                                                    float* __restrict__ out, int N){
  const int n = blockIdx.x;
  const int t = threadIdx.x;
  const int s = off[n], e1 = off[n+1];
  float a0 = 0.f, a1 = 0.f;
  for (int i=s; i<e1; ++i){
    const float* m = msg + (size_t)eid[i]*FEATD;
    a0 += m[t];
    if (t < 8) a1 += m[64+t];
  }
  out[(size_t)n*FEATD + t] = a0;
  if (t < 8) out[(size_t)n*FEATD + 64 + t] = a1;
}

// ---------------------------------------------------------------------------
// Fused GEMM+TP. 256 threads = 4 waves; 64 edges/block; role r owns u-rows
// {2r,2r+1}. Message accumulator in LDS (msg layout); no cross-phase register
// arrays except hf[4].
// ---------------------------------------------------------------------------
#define RTP 67   // consume role stride 16*67 ≡ 16 mod 32 -> 2-way (68 would be 0 mod 32 -> 4-way)

constexpr int OF_W3  = 0;         // 64*136 bf16 = 17408
constexpr int OF_RT  = 17408;     // 64*67 f32   = 17152
constexpr int OF_ACC = 34560;     // 64*72 f32   = 18432
constexpr int OF_F   = 52992;     // 64*74 bf16  = 9472
constexpr int OF_RSH = 62464;     // 64*25 f32   = 6400
constexpr int OF_KV  = 68864;     // 64*26 f32   = 6656
constexpr int OF_C3  = 75520;     // 1225 f32    = 4900
constexpr int OF_SRC = 80420;     // 64 int      = 256
constexpr int SMEM_SZ = 80676;    // < 81920 -> 2 blocks/CU

template<int LO,int LI,int LF>
__device__ __forceinline__ void phase(
    int chunk, const __hip_bfloat16* __restrict__ W3t,
    const bf16x8 (&hf)[4],
    __hip_bfloat16* sW3, float* sRt, __hip_bfloat16* sF,
    float* sRsh, float* sKV, const float* sC3, float* sAcc, int t)
{
  constexpr int NO = 2*LO+1, NI = 2*LI+1, NF = 2*LF+1;
  constexpr int C3B = C3OFFT[LO][LI][LF];
  constexpr int FO  = FOFFT[LI];

  __syncthreads();   // [A] prev consume done: sW3/sKV/sRt free

  // ---- 1. stage this chunk's 64 W3t rows (17408 B) ----
  {
    const float4* g = (const float4*)(W3t + (size_t)chunk*64*136);
    float4* s = (float4*)sW3;
    for (int p=t; p<1088; p+=256) s[p] = g[p];
  }
  // ---- 2. cooperative kv[e][o*NI+mi] = sum_mf C3 * y ----
  {
    const int le = t & 63, wv = t >> 6;
    float y[NF];
    #pragma unroll
    for (int mf=0; mf<NF; ++mf) y[mf] = sRsh[le*25 + LF*LF + mf];
    for (int it = wv; it < NO*NI; it += 4){
      float s = 0.f;
      #pragma unroll
      for (int mf=0; mf<NF; ++mf) s += sC3[C3B + it*NF + mf] * y[mf];
      sKV[le*26 + it] = s;
    }
  }
  __syncthreads();   // [B] sW3 + sKV visible

  // ---- 3. MFMA: Rt_chunk[c=uv][e], 64x64, K=128; B-operand from registers ----
  {
    const int lane = t & 63, wv = t >> 6;
    const int lr = lane & 15, lq = lane >> 4;
    f32x4 a4[4] = {};
    #pragma unroll
    for (int ks=0; ks<4; ++ks){
      #pragma unroll
      for (int ct=0; ct<4; ++ct){
        bf16x8 a = *(const bf16x8*)&sW3[(ct*16+lr)*136 + ks*32 + lq*8];
        a4[ct] = __builtin_amdgcn_mfma_f32_16x16x32_bf16(a, hf[ks], a4[ct], 0, 0, 0);
      }
    }
    #pragma unroll
    for (int ct=0; ct<4; ++ct)
      #pragma unroll
      for (int r=0; r<4; ++r)
        sRt[(ct*16 + lq*4 + r)*RTP + wv*16 + lr] = a4[ct][r];
  }
  __syncthreads();   // [C] sRt visible

  // ---- 4. TP consume: role owns u in {2*role,2*role+1}; accumulate into
  //         part[] (phase-local), single LDS RMW per (u,o) at the end ----
  {
    const int e = t >> 2, role = t & 3;
    float part[2][NO];
    #pragma unroll
    for (int du=0; du<2; ++du)
      #pragma unroll
      for (int o=0; o<NO; ++o) part[du][o] = 0.f;

    #pragma unroll
    for (int vg=0; vg<2; ++vg){
      float Fv[4][NI];
      #pragma unroll
      for (int v=0; v<4; ++v)
        #pragma unroll
        for (int mi=0; mi<NI; ++mi)
          Fv[v][mi] = __bfloat162float(sF[e*74 + FO + (vg*4+v)*NI + mi]);
      float tmp[4][NO];
      #pragma unroll
      for (int v=0; v<4; ++v)
        #pragma unroll
        for (int o=0; o<NO; ++o) tmp[v][o] = 0.f;
      #pragma unroll
      for (int o=0; o<NO; ++o)
        #pragma unroll
        for (int mi=0; mi<NI; ++mi){
          float kvv = sKV[e*26 + o*NI + mi];
          #pragma unroll
          for (int v=0; v<4; ++v) tmp[v][o] += kvv * Fv[v][mi];
        }
      #pragma unroll
      for (int du=0; du<2; ++du){
        const int u = role*2 + du;
        #pragma unroll
        for (int v=0; v<4; ++v){
          float r = sRt[(u*8 + vg*4 + v)*RTP + e];
          #pragma unroll
          for (int o=0; o<NO; ++o) part[du][o] += r * tmp[v][o];
        }
      }
    }
    #pragma unroll
    for (int du=0; du<2; ++du){
      const int u = role*2 + du;
      const int base = e*72 + ((LO==0) ? u : (LO==1) ? 8 + u*3 : 32 + u*5);
      #pragma unroll
      for (int o=0; o<NO; ++o) sAcc[base + o] += part[du][o];
    }
  }
}

__global__ __launch_bounds__(256,2) void fused_kernel(
    const float* __restrict__ feats, const int* __restrict__ ei,
    const float* __restrict__ rsh, const __hip_bfloat16* __restrict__ h_bf,
    const __hip_bfloat16* __restrict__ W3t, const float* __restrict__ C3g,
    float* __restrict__ msg, int E)
{
  __shared__ __align__(16) char smem[SMEM_SZ];
  __hip_bfloat16* sW3 = (__hip_bfloat16*)(smem + OF_W3);
  float* sRt  = (float*)(smem + OF_RT);
  float* sAcc = (float*)(smem + OF_ACC);
  __hip_bfloat16* sF = (__hip_bfloat16*)(smem + OF_F);
  float* sRsh = (float*)(smem + OF_RSH);
  float* sKV  = (float*)(smem + OF_KV);
  float* sC3  = (float*)(smem + OF_C3);
  int*   sSrc = (int*)(smem + OF_SRC);

  const int t = threadIdx.x;
  const int eb = blockIdx.x*64;

  // ---- h fragments into registers (B-operand, fixed across all 19 phases) ----
  bf16x8 hf[4];
  {
    const int lane = t & 63, wv = t >> 6;
    const int lr = lane & 15, lq = lane >> 4;
    const __hip_bfloat16* hrow = h_bf + (size_t)(eb + wv*16 + lr)*136;
    #pragma unroll
    for (int ks=0; ks<4; ++ks)
      hf[ks] = *(const bf16x8*)&hrow[ks*32 + lq*8];
  }
  // ---- prologue staging ----
  for (int p=t; p<4608; p+=256) sAcc[p] = 0.f;
  for (int p=t; p<64; p+=256){
    int e = eb + p;
    sSrc[p] = (e < E) ? ei[e] : 0;
  }
  for (int p=t; p<1600; p+=256){
    int el = p/25, j = p%25;
    int e = eb + el;
    sRsh[el*25 + j] = (e < E) ? rsh[(size_t)e*25 + j] : 0.f;
  }
  for (int p=t; p<C3TOT; p+=256) sC3[p] = C3g[p];
  __syncthreads();
  for (int p=t; p<64*72; p+=256){
    int el = p/72, j = p%72;
    sF[el*74 + j] = __float2bfloat16(feats[(size_t)sSrc[el]*72 + j]);
  }
  // (sF/sAcc consumed only after phase 0's internal barriers)

  // ---- 19 phases ----
  phase<0,0,0>( 0, W3t, hf, sW3, sRt, sF, sRsh, sKV, sC3, sAcc, t);
  phase<0,1,1>( 1, W3t, hf, sW3, sRt, sF, sRsh, sKV, sC3, sAcc, t);
  phase<0,2,2>( 2, W3t, hf, sW3, sRt, sF, sRsh, sKV, sC3, sAcc, t);
  phase<1,0,1>( 3, W3t, hf, sW3, sRt, sF, sRsh, sKV, sC3, sAcc, t);
  phase<1,1,0>( 4, W3t, hf, sW3, sRt, sF, sRsh, sKV, sC3, sAcc, t);
  phase<1,1,1>( 5, W3t, hf, sW3, sRt, sF, sRsh, sKV, sC3, sAcc, t);
  phase<1,1,2>( 6, W3t, hf, sW3, sRt, sF, sRsh, sKV, sC3, sAcc, t);
  phase<1,2,1>( 7, W3t, hf, sW3, sRt, sF, sRsh, sKV, sC3, sAcc, t);
  phase<1,2,2>( 8, W3t, hf, sW3, sRt, sF, sRsh, sKV, sC3, sAcc, t);
  phase<1,2,3>( 9, W3t, hf, sW3, sRt, sF, sRsh, sKV, sC3, sAcc, t);
  phase<2,0,2>(10, W3t, hf, sW3, sRt, sF, sRsh, sKV, sC3, sAcc, t);
  phase<2,1,1>(11, W3t, hf, sW3, sRt, sF, sRsh, sKV, sC3, sAcc, t);
  phase<2,1,2>(12, W3t, hf, sW3, sRt, sF, sRsh, sKV, sC3, sAcc, t);
  phase<2,1,3>(13, W3t, hf, sW3, sRt, sF, sRsh, sKV, sC3, sAcc, t);
  phase<2,2,0>(14, W3t, hf, sW3, sRt, sF, sRsh, sKV, sC3, sAcc, t);
  phase<2,2,1>(15, W3t, hf, sW3, sRt, sF, sRsh, sKV, sC3, sAcc, t);
  phase<2,2,2>(16, W3t, hf, sW3, sRt, sF, sRsh, sKV, sC3, sAcc, t);
  phase<2,2,3>(17, W3t, hf, sW3, sRt, sF, sRsh, sKV, sC3, sAcc, t);
  phase<2,2,4>(18, W3t, hf, sW3, sRt, sF, sRsh, sKV, sC3, sAcc, t);

  __syncthreads();   // final consume done: sAcc complete

  // ---- epilogue: normalize during coalesced float4 stream-out ----
  {
    const float4* sm = (const float4*)sAcc;
    float4* gm = (float4*)(msg + (size_t)eb*FEATD);
    for (int p=t; p<1152; p+=256){
      int j4 = p % 18;   // float4 index within a 72-float row
      float n = (j4 < 2) ? 0.72360125f : (j4 < 8) ? 0.8204867f : 0.9341652f;
      float4 v = sm[p];
      v.x *= n; v.y *= n; v.z *= n; v.w *= n;
      gm[p] = v;
    }
  }
}

// ---------------------------------------------------------------------------
extern "C" void kernel_launch(void* const* d_in, const int* in_sizes, int n_in,
                              void* d_out, int out_size, void* d_ws, size_t ws_size,
                              hipStream_t stream)
{
  const float* feats = (const float*)d_in[0];
  const int*   ei    = (const int*)d_in[1];
  const float* radii = (const float*)d_in[2];
  const float* rsh   = (const float*)d_in[3];
  const float* W0    = (const float*)d_in[4];
  const float* W1    = (const float*)d_in[5];
  const float* W2    = (const float*)d_in[6];
  const float* W3    = (const float*)d_in[7];
  float* out = (float*)d_out;
  const int E = in_sizes[2];
  const int N = in_sizes[0]/FEATD;

  const int EPAD = ((E + 63)/64)*64;
  const int NBLK = EPAD/64;

  char* ws = (char*)d_ws;
  size_t off_b = 0;
  float*  C3f = (float*)(ws + off_b);  off_b += 8192;
  double* Tre = (double*)(ws + off_b); off_b += 12288;
  double* Tim = (double*)(ws + off_b); off_b += 12288;          // 32768
  __hip_bfloat16* W3t  = (__hip_bfloat16*)(ws + off_b); off_b += 335872;  // 368640
  __hip_bfloat16* h_bf = (__hip_bfloat16*)(ws + off_b); off_b += (size_t)EPAD*272;
  float* msg = (float*)(ws + off_b);   off_b += (size_t)EPAD*FEATD*4;
  int* deg    = (int*)(ws + off_b);    off_b += (size_t)N*4;
  int* offv   = (int*)(ws + off_b);    off_b += (size_t)(N+1)*4;
  int* cursor = (int*)(ws + off_b);    off_b += (size_t)N*4;
  int* eid    = (int*)(ws + off_b);    off_b += (size_t)E*4;

  // constants / tables
  c3_build_kernel<<<dim3((C3TOT+63)/64), dim3(64), 0, stream>>>(Tre, Tim);
  c3_norm_kernel<<<dim3(NCOMBO), dim3(64), 0, stream>>>(Tre, Tim, C3f);
  prep_w3t_kernel<<<dim3((1216*136+255)/256), dim3(256), 0, stream>>>(W3, W3t);

  // CSR of edges by target
  hipMemsetAsync(deg, 0, (size_t)N*4, stream);
  hist_kernel<<<dim3((E+255)/256), dim3(256), 0, stream>>>(ei, deg, E);
  scan_kernel<<<dim3(1), dim3(256), 0, stream>>>(deg, offv, cursor, N, E);
  fill_kernel<<<dim3((E+255)/256), dim3(256), 0, stream>>>(ei, cursor, eid, E);

  // main pipeline
  radial_hidden_kernel<<<dim3(NBLK), dim3(256), 0, stream>>>(radii, W0, W1, W2, h_bf, E);
  fused_kernel<<<dim3(NBLK), dim3(256), 0, stream>>>(feats, ei, rsh, h_bf, W3t, C3f, msg, E);
  gather_kernel<<<dim3(N), dim3(64), 0, stream>>>(msg, offv, eid, out, N);
}

// Round 11
// 515.648 us; speedup vs baseline: 2.0526x; 1.2374x over previous
//
#include <hip/hip_runtime.h>
#include <hip/hip_bf16.h>
#include <math.h>

// ============================================================================
// MinimalNetwork, round 11: barrier-free fused main loop.
// All per-edge state (sRt, sKV, sAcc, rsh, F, hf) is wave-local: wave wv owns
// edges [16wv,16wv+16). The only cross-wave coupling was the sW3 LDS staging
// -> MFMA A-operand now reads W3t directly from global (L1/L2-resident,
// full-cacheline access pattern). kv split is quad-local. Per-wave in-order
// LDS + wave_barrier() replaces all 57 __syncthreads in the 19-phase loop.
// radial: W0/W1/W2 read from global (scale post-accum), LDS 53.8 KB -> 3 blk/CU.
// ============================================================================

#define FEATD 72
#define NCOL 1216
#define SWISH_SCALE 1.679177f

typedef __attribute__((ext_vector_type(8))) short bf16x8;
typedef __attribute__((ext_vector_type(4))) float f32x4;

// ---- 19 (lo,li,lf) chunks; CB_OFF = offsets into the C3 coefficient pool ----
constexpr int NCOMBO = 19;
constexpr int CB_LO[NCOMBO] = {0,0,0,1,1,1,1,1,1,1,2,2,2,2,2,2,2,2,2};
constexpr int CB_LI[NCOMBO] = {0,1,2,0,1,1,1,2,2,2,0,1,1,1,2,2,2,2,2};
constexpr int CB_LF[NCOMBO] = {0,1,2,1,0,1,2,1,2,3,2,1,2,3,0,1,2,3,4};
constexpr int CB_OFF[NCOMBO] = {0,1,10,35,44,53,80,125,170,245,350,375,420,495,600,625,700,825,1000};
constexpr int CB_SZ[NCOMBO]  = {1,9,25,9,9,27,45,45,75,105,25,45,75,105,25,75,125,175,225};
constexpr int C3TOT = 1225;

constexpr int C3OFFT[3][3][5] = {
  { {0,-1,-1,-1,-1}, {-1,1,-1,-1,-1}, {-1,-1,10,-1,-1} },
  { {-1,35,-1,-1,-1}, {44,53,80,-1,-1}, {-1,125,170,245,-1} },
  { {-1,-1,350,-1,-1}, {-1,375,420,495,-1}, {600,625,700,825,1000} }
};
constexpr int ROFFT[3][3] = {{0,64,128},{192,256,448},{640,704,896}};
constexpr int FOFFT[3]   = {0,8,32};

__device__ const double d_fact[11] = {1.,1.,2.,6.,24.,120.,720.,5040.,40320.,362880.,3628800.};

// ---------------------------------------------------------------------------
// Wigner 3j (complex basis, Racah) in double precision + real change of basis
// ---------------------------------------------------------------------------
__device__ double w3j_entry(int j1,int j2,int j3,int m1,int m2,int m3){
  if (m1+m2+m3 != 0) return 0.0;
  int dj = j1-j2; if (dj<0) dj=-dj;
  if (j3 < dj || j3 > j1+j2) return 0.0;
  int t1 = j2 - m1 - j3, t2 = j1 + m2 - j3;
  int kmin = 0; if (t1>kmin) kmin=t1; if (t2>kmin) kmin=t2;
  int kmax = j1+j2-j3; if (j1-m1<kmax) kmax=j1-m1; if (j2+m2<kmax) kmax=j2+m2;
  double s = 0.0;
  for (int k=kmin;k<=kmax;++k){
    double den = d_fact[k]*d_fact[k-t1]*d_fact[k-t2]*d_fact[j1+j2-j3-k]
               * d_fact[j1-m1-k]*d_fact[j2+m2-k];
    s += ((k&1)? -1.0:1.0)/den;
  }
  double pref = sqrt(d_fact[j1+j2-j3]*d_fact[j1-j2+j3]*d_fact[-j1+j2+j3]/d_fact[j1+j2+j3+1]
               * d_fact[j1+m1]*d_fact[j1-m1]*d_fact[j2+m2]*d_fact[j2-m2]
               * d_fact[j3+m3]*d_fact[j3-m3]);
  int ex = j1-j2-m3;
  if (ex & 1) pref = -pref;
  return pref*s;
}

__device__ void cob(int l, int r, int c, double& re, double& im){
  re = 0.0; im = 0.0;
  int mr = r - l, mc = c - l;
  const double s = 0.70710678118654752440;
  if (mr == 0) { if (mc == 0) re = 1.0; return; }
  if (mr > 0) {
    if (mc == mr)       re = (mr & 1) ? -s : s;
    else if (mc == -mr) re = s;
  } else {
    int m = -mr;
    if (mc == -m)      im = s;
    else if (mc == m)  im = (m & 1) ? s : -s;
  }
}

__global__ void c3_build_kernel(double* __restrict__ Tre, double* __restrict__ Tim){
  int idx = blockIdx.x*64 + threadIdx.x;
  if (idx >= C3TOT) return;
  int c = 0;
  while (c+1 < NCOMBO && idx >= CB_OFF[c+1]) ++c;
  int lo = CB_LO[c], li = CB_LI[c], lf = CB_LF[c];
  int n2 = 2*li+1, n3 = 2*lf+1;
  int loc = idx - CB_OFF[c];
  int a = loc/(n2*n3), b = (loc/n3)%n2, g = loc%n3;
  double sre=0.0, sim=0.0;
  for (int m1=-lo; m1<=lo; ++m1){
    for (int m2=-li; m2<=li; ++m2){
      int m3 = -m1-m2;
      if (m3 < -lf || m3 > lf) continue;
      double w = w3j_entry(lo,li,lf,m1,m2,m3);
      if (w == 0.0) continue;
      double r1,i1,r2,i2,r3,i3;
      cob(lo, a, m1+lo, r1,i1);
      cob(li, b, m2+li, r2,i2);
      cob(lf, g, m3+lf, r3,i3);
      double rr = r1*r2 - i1*i2, ri = r1*i2 + i1*r2;
      double fr = rr*r3 - ri*i3, fi = rr*i3 + ri*r3;
      sre += fr*w; sim += fi*w;
    }
  }
  Tre[idx] = sre; Tim[idx] = sim;
}

__global__ void c3_norm_kernel(const double* __restrict__ Tre, const double* __restrict__ Tim,
                               float* __restrict__ C3f){
  int c = blockIdx.x;
  int off = CB_OFF[c], sz = CB_SZ[c];
  int t = threadIdx.x;
  double sre=0.0, sim=0.0;
  for (int p=t; p<sz; p+=64){ double x=Tre[off+p], y=Tim[off+p]; sre+=x*x; sim+=y*y; }
  for (int m=1; m<64; m<<=1){ sre += __shfl_xor(sre, m, 64); sim += __shfl_xor(sim, m, 64); }
  bool useRe = (sre >= sim);
  double n = sqrt(useRe ? sre : sim);
  double inv = (n > 0.0) ? 1.0/n : 1.0;
  for (int p=t; p<sz; p+=64){
    double v = useRe ? Tre[off+p] : Tim[off+p];
    C3f[off+p] = (float)(v*inv);
  }
}

// ---------------------------------------------------------------------------
// W3t[c'][k], c' chunk-major: c' = chunk*64 + uv maps to original column
// ROFFT[lo][li] + uv*nlf + fi. 0.1 scale folded. Pitch 136, pad k>=100 = 0.
// ---------------------------------------------------------------------------
__global__ __launch_bounds__(256) void prep_w3t_kernel(const float* __restrict__ W3,
                                                       __hip_bfloat16* __restrict__ W3t){
  int idx = blockIdx.x*256 + threadIdx.x;
  if (idx >= 1216*136) return;
  int cp = idx/136, k = idx%136;
  int chunk = cp>>6, uv = cp&63;
  int lo = CB_LO[chunk], li = CB_LI[chunk], lf = CB_LF[chunk];
  int lmin = lo<li ? lo : li;
  int nlf = 2*lmin+1;
  int fi = lf - (lo>li ? lo-li : li-lo);
  int c = ROFFT[lo][li] + uv*nlf + fi;
  float v = (k < 100) ? 0.1f*W3[(size_t)k*NCOL + c] : 0.f;
  W3t[idx] = __float2bfloat16(v);
}

// ---------------------------------------------------------------------------
// Radial hidden chain -> h_bf[e][136] bf16. Weights read directly from global
// (L1/L2-resident, broadcast across blocks); scales applied post-accumulation.
// LDS = 53.8 KB -> 3 blocks/CU.
// ---------------------------------------------------------------------------
__device__ __forceinline__ float swishf(float s){
  return SWISH_SCALE * s / (1.f + __expf(-s));
}

__global__ __launch_bounds__(256,3) void radial_hidden_kernel(
    const float* __restrict__ radii,
    const float* __restrict__ W0, const float* __restrict__ W1, const float* __restrict__ W2,
    __hip_bfloat16* __restrict__ h_bf, int E)
{
  __shared__ __align__(16) float sX[6400];   // [er][k] pitch 100; reused as bf16 staging
  __shared__ float sY[6400];
  __shared__ float sbas[640];
  const int t = threadIdx.x;
  const int et0 = blockIdx.x*64;

  for (int p=t; p<640; p+=256){
    int er = p/10, k = p%10;
    int eg = et0 + er;
    float r = (eg < E) ? radii[eg] : 0.f;
    float c = 0.7f + (2.5f/9.0f)*(float)k;
    float d = (r - c) * (9.0f/2.5f);
    sbas[p] = __expf(-d*d);
  }
  __syncthreads();
  // layer 1 (K=10), W0 4 KB L1-resident
  for (int p=t; p<6400; p+=256){
    int er = p/100, o = p%100;
    float s = 0.f;
    #pragma unroll
    for (int k=0;k<10;++k) s += sbas[er*10+k]*W0[k*100+o];
    sX[p] = swishf(s*0.3162277660168379f);   // 1/sqrt(10)
  }
  __syncthreads();
  // layer 2 (K=100), W1 from global
  for (int q=t; q<400; q+=256){
    int erb = (q/25)*4, ob = (q%25)*4;
    float acc[4][4] = {};
    for (int k=0;k<100;++k){
      float4 w = *(const float4*)&W1[k*100+ob];
      #pragma unroll
      for (int i=0;i<4;++i){
        float a = sX[(erb+i)*100+k];
        acc[i][0]+=a*w.x; acc[i][1]+=a*w.y; acc[i][2]+=a*w.z; acc[i][3]+=a*w.w;
      }
    }
    #pragma unroll
    for (int i=0;i<4;++i){
      float4 v = make_float4(swishf(acc[i][0]*0.1f),swishf(acc[i][1]*0.1f),
                             swishf(acc[i][2]*0.1f),swishf(acc[i][3]*0.1f));
      *(float4*)&sY[(erb+i)*100+ob] = v;
    }
  }
  __syncthreads();   // layer2 done reading sX -> reusable as bf16 staging

  __hip_bfloat16* sHB = (__hip_bfloat16*)sX;   // 17408 B <= 25600 B
  for (int p=t; p<64*36; p+=256){
    int er = p/36, k = 100 + p%36;
    sHB[er*136 + k] = __float2bfloat16(0.f);
  }
  // layer 3 (K=100), W2 from global, bf16 out into LDS staging
  for (int q=t; q<400; q+=256){
    int erb = (q/25)*4, ob = (q%25)*4;
    float acc[4][4] = {};
    for (int k=0;k<100;++k){
      float4 w = *(const float4*)&W2[k*100+ob];
      #pragma unroll
      for (int i=0;i<4;++i){
        float a = sY[(erb+i)*100+k];
        acc[i][0]+=a*w.x; acc[i][1]+=a*w.y; acc[i][2]+=a*w.z; acc[i][3]+=a*w.w;
      }
    }
    #pragma unroll
    for (int i=0;i<4;++i){
      __hip_bfloat16 hv[4];
      #pragma unroll
      for (int j=0;j<4;++j) hv[j] = __float2bfloat16(swishf(acc[i][j]*0.1f));
      *(short4*)&sHB[(erb+i)*136 + ob] = *(short4*)hv;
    }
  }
  __syncthreads();
  {
    const float4* sm = (const float4*)sHB;
    float4* gm = (float4*)(h_bf + (size_t)et0*136);
    for (int p=t; p<1088; p+=256) gm[p] = sm[p];
  }
}

// ---------------------------------------------------------------------------
// CSR of edges by target node
// ---------------------------------------------------------------------------
__global__ __launch_bounds__(256) void hist_kernel(const int* __restrict__ ei,
                                                   int* __restrict__ deg, int E){
  int e = blockIdx.x*256 + threadIdx.x;
  if (e < E) atomicAdd(&deg[ei[E+e]], 1);
}

__global__ __launch_bounds__(256) void scan_kernel(const int* __restrict__ deg,
                                                   int* __restrict__ off,
                                                   int* __restrict__ cursor, int N, int E){
  __shared__ int part[256], spref[256];
  const int t = threadIdx.x;
  const int CH = (N + 255)/256;
  int lo = t*CH, hi = lo+CH < N ? lo+CH : N;
  int s = 0;
  for (int n=lo; n<hi; ++n) s += deg[n];
  part[t] = s;
  __syncthreads();
  if (t == 0){
    int run = 0;
    for (int i=0;i<256;++i){ spref[i] = run; run += part[i]; }
  }
  __syncthreads();
  int run = spref[t];
  for (int n=lo; n<hi; ++n){ off[n] = run; cursor[n] = run; run += deg[n]; }
  if (t == 255) off[N] = E;
}

__global__ __launch_bounds__(256) void fill_kernel(const int* __restrict__ ei,
                                                   int* __restrict__ cursor,
                                                   int* __restrict__ eid, int E){
  int e = blockIdx.x*256 + threadIdx.x;
  if (e < E){
    int idx = atomicAdd(&cursor[ei[E+e]], 1);
    eid[idx] = e;
  }
}

// ---------------------------------------------------------------------------
// Gather: one 64-lane wave per node; writes every output element exactly once.
// ---------------------------------------------------------------------------
__global__ __launch_bounds__(64) void gather_kernel(const float* __restrict__ msg,
                                                    const int* __restrict__ off,
                                                    const int* __restrict__ eid,
                                                    float* __restrict__ out, int N){
  const int n = blockIdx.x;
  const int t = threadIdx.x;
  const int s = off[n], e1 = off[n+1];
  float a0 = 0.f, a1 = 0.f;
  for (int i=s; i<e1; ++i){
    const float* m = msg + (size_t)eid[i]*FEATD;
    a0 += m[t];
    if (t < 8) a1 += m[64+t];
  }
  out[(size_t)n*FEATD + t] = a0;
  if (t < 8) out[(size_t)n*FEATD + 64 + t] = a1;
}

// ---------------------------------------------------------------------------
// Fused GEMM+TP, barrier-free main loop. 256 threads = 4 waves; 64 edges/block.
// Wave wv owns edges [16wv,16wv+16): kv (quad-split), MFMA columns, sRt, sAcc
// are all wave-local. W3t A-operand read directly from global (L1/L2).
// ---------------------------------------------------------------------------
#define RTP 67   // consume role stride 2*8*67 ≡ 16 mod 32 -> 2-way (free)

constexpr int OF_RT  = 0;         // 64*67 f32 = 17152
constexpr int OF_ACC = 17152;     // 64*72 f32 = 18432
constexpr int OF_F   = 35584;     // 64*74 bf16 = 9472
constexpr int OF_RSH = 45056;     // 64*25 f32 = 6400
constexpr int OF_KV  = 51456;     // 64*26 f32 = 6656
constexpr int OF_C3  = 58112;     // 1225 f32 = 4900
constexpr int OF_SRC = 63012;     // 64 int = 256
constexpr int SMEM_SZ = 63268;    // 63.3 KB -> 2 blocks/CU

template<int LO,int LI,int LF>
__device__ __forceinline__ void phase(
    int chunk, const __hip_bfloat16* __restrict__ W3t, const bf16x8 (&hf)[4],
    float* sRt, __hip_bfloat16* sF, float* sRsh, float* sKV, const float* sC3,
    float* sAcc, int t)
{
  constexpr int NO = 2*LO+1, NI = 2*LI+1, NF = 2*LF+1;
  constexpr int C3B = C3OFFT[LO][LI][LF];
  constexpr int FO  = FOFFT[LI];

  const int e = t >> 2, role = t & 3;       // wave-local edge ownership
  const int lane = t & 63, wv = t >> 6;
  const int lr = lane & 15, lq = lane >> 4;

  // ---- 1. kv[e][o*NI+mi] = sum_mf C3 * y : quad-split (wave-local, no barrier)
  {
    float y[NF];
    #pragma unroll
    for (int mf=0; mf<NF; ++mf) y[mf] = sRsh[e*25 + LF*LF + mf];
    for (int it = role; it < NO*NI; it += 4){
      float s = 0.f;
      #pragma unroll
      for (int mf=0; mf<NF; ++mf) s += sC3[C3B + it*NF + mf] * y[mf];
      sKV[e*26 + it] = s;
    }
  }
  // ---- 2. MFMA: Rt[c=0..63][e in wave's 16 cols]; A straight from global ----
  {
    const __hip_bfloat16* wb = W3t + (size_t)chunk*64*136;
    f32x4 a4[4] = {};
    #pragma unroll
    for (int ks=0; ks<4; ++ks){
      #pragma unroll
      for (int ct=0; ct<4; ++ct){
        bf16x8 a = *(const bf16x8*)&wb[(ct*16+lr)*136 + ks*32 + lq*8];
        a4[ct] = __builtin_amdgcn_mfma_f32_16x16x32_bf16(a, hf[ks], a4[ct], 0, 0, 0);
      }
    }
    #pragma unroll
    for (int ct=0; ct<4; ++ct)
      #pragma unroll
      for (int r=0; r<4; ++r)
        sRt[(ct*16 + lq*4 + r)*RTP + wv*16 + lr] = a4[ct][r];
  }
  __builtin_amdgcn_wave_barrier();   // pin LDS program order (writes above, reads below)

  // ---- 3. TP consume: role owns u in {2*role,2*role+1}; all wave-local ----
  {
    float part[2][NO];
    #pragma unroll
    for (int du=0; du<2; ++du)
      #pragma unroll
      for (int o=0; o<NO; ++o) part[du][o] = 0.f;

    #pragma unroll
    for (int vg=0; vg<2; ++vg){
      float Fv[4][NI];
      #pragma unroll
      for (int v=0; v<4; ++v)
        #pragma unroll
        for (int mi=0; mi<NI; ++mi)
          Fv[v][mi] = __bfloat162float(sF[e*74 + FO + (vg*4+v)*NI + mi]);
      float tmp[4][NO];
      #pragma unroll
      for (int v=0; v<4; ++v)
        #pragma unroll
        for (int o=0; o<NO; ++o) tmp[v][o] = 0.f;
      #pragma unroll
      for (int o=0; o<NO; ++o)
        #pragma unroll
        for (int mi=0; mi<NI; ++mi){
          float kvv = sKV[e*26 + o*NI + mi];
          #pragma unroll
          for (int v=0; v<4; ++v) tmp[v][o] += kvv * Fv[v][mi];
        }
      #pragma unroll
      for (int du=0; du<2; ++du){
        const int u = role*2 + du;
        #pragma unroll
        for (int v=0; v<4; ++v){
          float r = sRt[(u*8 + vg*4 + v)*RTP + e];
          #pragma unroll
          for (int o=0; o<NO; ++o) part[du][o] += r * tmp[v][o];
        }
      }
    }
    #pragma unroll
    for (int du=0; du<2; ++du){
      const int u = role*2 + du;
      const int base = e*72 + ((LO==0) ? u : (LO==1) ? 8 + u*3 : 32 + u*5);
      #pragma unroll
      for (int o=0; o<NO; ++o) sAcc[base + o] += part[du][o];
    }
  }
  __builtin_amdgcn_wave_barrier();   // consume reads done before next phase's writes
}

__global__ __launch_bounds__(256,2) void fused_kernel(
    const float* __restrict__ feats, const int* __restrict__ ei,
    const float* __restrict__ rsh, const __hip_bfloat16* __restrict__ h_bf,
    const __hip_bfloat16* __restrict__ W3t, const float* __restrict__ C3g,
    float* __restrict__ msg, int E)
{
  __shared__ __align__(16) char smem[SMEM_SZ];
  float* sRt  = (float*)(smem + OF_RT);
  float* sAcc = (float*)(smem + OF_ACC);
  __hip_bfloat16* sF = (__hip_bfloat16*)(smem + OF_F);
  float* sRsh = (float*)(smem + OF_RSH);
  float* sKV  = (float*)(smem + OF_KV);
  float* sC3  = (float*)(smem + OF_C3);
  int*   sSrc = (int*)(smem + OF_SRC);

  const int t = threadIdx.x;
  const int eb = blockIdx.x*64;

  // ---- h fragments into registers (B-operand, fixed across all 19 phases) ----
  bf16x8 hf[4];
  {
    const int lane = t & 63, wv = t >> 6;
    const int lr = lane & 15, lq = lane >> 4;
    const __hip_bfloat16* hrow = h_bf + (size_t)(eb + wv*16 + lr)*136;
    #pragma unroll
    for (int ks=0; ks<4; ++ks)
      hf[ks] = *(const bf16x8*)&hrow[ks*32 + lq*8];
  }
  // ---- prologue staging (striped, cross-wave -> two barriers total) ----
  for (int p=t; p<4608; p+=256) sAcc[p] = 0.f;
  for (int p=t; p<64; p+=256){
    int e = eb + p;
    sSrc[p] = (e < E) ? ei[e] : 0;
  }
  for (int p=t; p<1600; p+=256){
    int el = p/25, j = p%25;
    int e = eb + el;
    sRsh[el*25 + j] = (e < E) ? rsh[(size_t)e*25 + j] : 0.f;
  }
  for (int p=t; p<C3TOT; p+=256) sC3[p] = C3g[p];
  __syncthreads();
  for (int p=t; p<64*72; p+=256){
    int el = p/72, j = p%72;
    sF[el*74 + j] = __float2bfloat16(feats[(size_t)sSrc[el]*72 + j]);
  }
  __syncthreads();   // sF visible; main loop below is barrier-free

  // ---- 19 phases, no __syncthreads ----
  phase<0,0,0>( 0, W3t, hf, sRt, sF, sRsh, sKV, sC3, sAcc, t);
  phase<0,1,1>( 1, W3t, hf, sRt, sF, sRsh, sKV, sC3, sAcc, t);
  phase<0,2,2>( 2, W3t, hf, sRt, sF, sRsh, sKV, sC3, sAcc, t);
  phase<1,0,1>( 3, W3t, hf, sRt, sF, sRsh, sKV, sC3, sAcc, t);
  phase<1,1,0>( 4, W3t, hf, sRt, sF, sRsh, sKV, sC3, sAcc, t);
  phase<1,1,1>( 5, W3t, hf, sRt, sF, sRsh, sKV, sC3, sAcc, t);
  phase<1,1,2>( 6, W3t, hf, sRt, sF, sRsh, sKV, sC3, sAcc, t);
  phase<1,2,1>( 7, W3t, hf, sRt, sF, sRsh, sKV, sC3, sAcc, t);
  phase<1,2,2>( 8, W3t, hf, sRt, sF, sRsh, sKV, sC3, sAcc, t);
  phase<1,2,3>( 9, W3t, hf, sRt, sF, sRsh, sKV, sC3, sAcc, t);
  phase<2,0,2>(10, W3t, hf, sRt, sF, sRsh, sKV, sC3, sAcc, t);
  phase<2,1,1>(11, W3t, hf, sRt, sF, sRsh, sKV, sC3, sAcc, t);
  phase<2,1,2>(12, W3t, hf, sRt, sF, sRsh, sKV, sC3, sAcc, t);
  phase<2,1,3>(13, W3t, hf, sRt, sF, sRsh, sKV, sC3, sAcc, t);
  phase<2,2,0>(14, W3t, hf, sRt, sF, sRsh, sKV, sC3, sAcc, t);
  phase<2,2,1>(15, W3t, hf, sRt, sF, sRsh, sKV, sC3, sAcc, t);
  phase<2,2,2>(16, W3t, hf, sRt, sF, sRsh, sKV, sC3, sAcc, t);
  phase<2,2,3>(17, W3t, hf, sRt, sF, sRsh, sKV, sC3, sAcc, t);
  phase<2,2,4>(18, W3t, hf, sRt, sF, sRsh, sKV, sC3, sAcc, t);

  __syncthreads();   // sAcc complete across waves

  // ---- epilogue: normalize during coalesced float4 stream-out ----
  {
    const float4* sm = (const float4*)sAcc;
    float4* gm = (float4*)(msg + (size_t)eb*FEATD);
    for (int p=t; p<1152; p+=256){
      int j4 = p % 18;   // float4 index within a 72-float row
      float n = (j4 < 2) ? 0.72360125f : (j4 < 8) ? 0.8204867f : 0.9341652f;
      float4 v = sm[p];
      v.x *= n; v.y *= n; v.z *= n; v.w *= n;
      gm[p] = v;
    }
  }
}

// ---------------------------------------------------------------------------
extern "C" void kernel_launch(void* const* d_in, const int* in_sizes, int n_in,
                              void* d_out, int out_size, void* d_ws, size_t ws_size,
                              hipStream_t stream)
{
  const float* feats = (const float*)d_in[0];
  const int*   ei    = (const int*)d_in[1];
  const float* radii = (const float*)d_in[2];
  const float* rsh   = (const float*)d_in[3];
  const float* W0    = (const float*)d_in[4];
  const float* W1    = (const float*)d_in[5];
  const float* W2    = (const float*)d_in[6];
  const float* W3    = (const float*)d_in[7];
  float* out = (float*)d_out;
  const int E = in_sizes[2];
  const int N = in_sizes[0]/FEATD;

  const int EPAD = ((E + 63)/64)*64;
  const int NBLK = EPAD/64;

  char* ws = (char*)d_ws;
  size_t off_b = 0;
  float*  C3f = (float*)(ws + off_b);  off_b += 8192;
  double* Tre = (double*)(ws + off_b); off_b += 12288;
  double* Tim = (double*)(ws + off_b); off_b += 12288;          // 32768
  __hip_bfloat16* W3t  = (__hip_bfloat16*)(ws + off_b); off_b += 335872;  // 368640
  __hip_bfloat16* h_bf = (__hip_bfloat16*)(ws + off_b); off_b += (size_t)EPAD*272;
  float* msg = (float*)(ws + off_b);   off_b += (size_t)EPAD*FEATD*4;
  int* deg    = (int*)(ws + off_b);    off_b += (size_t)N*4;
  int* offv   = (int*)(ws + off_b);    off_b += (size_t)(N+1)*4;
  int* cursor = (int*)(ws + off_b);    off_b += (size_t)N*4;
  int* eid    = (int*)(ws + off_b);    off_b += (size_t)E*4;

  // constants / tables
  c3_build_kernel<<<dim3((C3TOT+63)/64), dim3(64), 0, stream>>>(Tre, Tim);
  c3_norm_kernel<<<dim3(NCOMBO), dim3(64), 0, stream>>>(Tre, Tim, C3f);
  prep_w3t_kernel<<<dim3((1216*136+255)/256), dim3(256), 0, stream>>>(W3, W3t);

  // CSR of edges by target
  hipMemsetAsync(deg, 0, (size_t)N*4, stream);
  hist_kernel<<<dim3((E+255)/256), dim3(256), 0, stream>>>(ei, deg, E);
  scan_kernel<<<dim3(1), dim3(256), 0, stream>>>(deg, offv, cursor, N, E);
  fill_kernel<<<dim3((E+255)/256), dim3(256), 0, stream>>>(ei, cursor, eid, E);

  // main pipeline
  radial_hidden_kernel<<<dim3(NBLK), dim3(256), 0, stream>>>(radii, W0, W1, W2, h_bf, E);
  fused_kernel<<<dim3(NBLK), dim3(256), 0, stream>>>(feats, ei, rsh, h_bf, W3t, C3f, msg, E);
  gather_kernel<<<dim3(N), dim3(64), 0, stream>>>(msg, offv, eid, out, N);
}

// Round 12
// 484.558 us; speedup vs baseline: 2.1843x; 1.0642x over previous
//
#include <hip/hip_runtime.h>
#include <hip/hip_bf16.h>
#include <math.h>

// ============================================================================
// MinimalNetwork, round 12: TP contraction reorder + b128 LDS.
//  - H-trick: H[u][mi] = sum_v R[u,v]*F[v,mi] (role-owned, no redundancy),
//    then s[o] = sum_mi kv[o,mi]*H[u,mi].  MACs/thread -45%.
//  - sRt stored [e][68] (272B pitch, m97 pattern): MFMA b128 writes, b128
//    consume reads.
//  - sF stored f32 pitch 76: F-block loads are b128, no bf16 cvt.
// Barrier-free main loop (r11), LDS accumulator (r10) retained.
// ============================================================================

#define FEATD 72
#define NCOL 1216
#define SWISH_SCALE 1.679177f

typedef __attribute__((ext_vector_type(8))) short bf16x8;
typedef __attribute__((ext_vector_type(4))) float f32x4;

// ---- 19 (lo,li,lf) chunks; CB_OFF = offsets into the C3 coefficient pool ----
constexpr int NCOMBO = 19;
constexpr int CB_LO[NCOMBO] = {0,0,0,1,1,1,1,1,1,1,2,2,2,2,2,2,2,2,2};
constexpr int CB_LI[NCOMBO] = {0,1,2,0,1,1,1,2,2,2,0,1,1,1,2,2,2,2,2};
constexpr int CB_LF[NCOMBO] = {0,1,2,1,0,1,2,1,2,3,2,1,2,3,0,1,2,3,4};
constexpr int CB_OFF[NCOMBO] = {0,1,10,35,44,53,80,125,170,245,350,375,420,495,600,625,700,825,1000};
constexpr int CB_SZ[NCOMBO]  = {1,9,25,9,9,27,45,45,75,105,25,45,75,105,25,75,125,175,225};
constexpr int C3TOT = 1225;

constexpr int C3OFFT[3][3][5] = {
  { {0,-1,-1,-1,-1}, {-1,1,-1,-1,-1}, {-1,-1,10,-1,-1} },
  { {-1,35,-1,-1,-1}, {44,53,80,-1,-1}, {-1,125,170,245,-1} },
  { {-1,-1,350,-1,-1}, {-1,375,420,495,-1}, {600,625,700,825,1000} }
};
constexpr int ROFFT[3][3] = {{0,64,128},{192,256,448},{640,704,896}};
constexpr int FOFFT[3]   = {0,8,32};

__device__ const double d_fact[11] = {1.,1.,2.,6.,24.,120.,720.,5040.,40320.,362880.,3628800.};

// ---------------------------------------------------------------------------
// Wigner 3j (complex basis, Racah) in double precision + real change of basis
// ---------------------------------------------------------------------------
__device__ double w3j_entry(int j1,int j2,int j3,int m1,int m2,int m3){
  if (m1+m2+m3 != 0) return 0.0;
  int dj = j1-j2; if (dj<0) dj=-dj;
  if (j3 < dj || j3 > j1+j2) return 0.0;
  int t1 = j2 - m1 - j3, t2 = j1 + m2 - j3;
  int kmin = 0; if (t1>kmin) kmin=t1; if (t2>kmin) kmin=t2;
  int kmax = j1+j2-j3; if (j1-m1<kmax) kmax=j1-m1; if (j2+m2<kmax) kmax=j2+m2;
  double s = 0.0;
  for (int k=kmin;k<=kmax;++k){
    double den = d_fact[k]*d_fact[k-t1]*d_fact[k-t2]*d_fact[j1+j2-j3-k]
               * d_fact[j1-m1-k]*d_fact[j2+m2-k];
    s += ((k&1)? -1.0:1.0)/den;
  }
  double pref = sqrt(d_fact[j1+j2-j3]*d_fact[j1-j2+j3]*d_fact[-j1+j2+j3]/d_fact[j1+j2+j3+1]
               * d_fact[j1+m1]*d_fact[j1-m1]*d_fact[j2+m2]*d_fact[j2-m2]
               * d_fact[j3+m3]*d_fact[j3-m3]);
  int ex = j1-j2-m3;
  if (ex & 1) pref = -pref;
  return pref*s;
}

__device__ void cob(int l, int r, int c, double& re, double& im){
  re = 0.0; im = 0.0;
  int mr = r - l, mc = c - l;
  const double s = 0.70710678118654752440;
  if (mr == 0) { if (mc == 0) re = 1.0; return; }
  if (mr > 0) {
    if (mc == mr)       re = (mr & 1) ? -s : s;
    else if (mc == -mr) re = s;
  } else {
    int m = -mr;
    if (mc == -m)      im = s;
    else if (mc == m)  im = (m & 1) ? s : -s;
  }
}

__global__ void c3_build_kernel(double* __restrict__ Tre, double* __restrict__ Tim){
  int idx = blockIdx.x*64 + threadIdx.x;
  if (idx >= C3TOT) return;
  int c = 0;
  while (c+1 < NCOMBO && idx >= CB_OFF[c+1]) ++c;
  int lo = CB_LO[c], li = CB_LI[c], lf = CB_LF[c];
  int n2 = 2*li+1, n3 = 2*lf+1;
  int loc = idx - CB_OFF[c];
  int a = loc/(n2*n3), b = (loc/n3)%n2, g = loc%n3;
  double sre=0.0, sim=0.0;
  for (int m1=-lo; m1<=lo; ++m1){
    for (int m2=-li; m2<=li; ++m2){
      int m3 = -m1-m2;
      if (m3 < -lf || m3 > lf) continue;
      double w = w3j_entry(lo,li,lf,m1,m2,m3);
      if (w == 0.0) continue;
      double r1,i1,r2,i2,r3,i3;
      cob(lo, a, m1+lo, r1,i1);
      cob(li, b, m2+li, r2,i2);
      cob(lf, g, m3+lf, r3,i3);
      double rr = r1*r2 - i1*i2, ri = r1*i2 + i1*r2;
      double fr = rr*r3 - ri*i3, fi = rr*i3 + ri*r3;
      sre += fr*w; sim += fi*w;
    }
  }
  Tre[idx] = sre; Tim[idx] = sim;
}

__global__ void c3_norm_kernel(const double* __restrict__ Tre, const double* __restrict__ Tim,
                               float* __restrict__ C3f){
  int c = blockIdx.x;
  int off = CB_OFF[c], sz = CB_SZ[c];
  int t = threadIdx.x;
  double sre=0.0, sim=0.0;
  for (int p=t; p<sz; p+=64){ double x=Tre[off+p], y=Tim[off+p]; sre+=x*x; sim+=y*y; }
  for (int m=1; m<64; m<<=1){ sre += __shfl_xor(sre, m, 64); sim += __shfl_xor(sim, m, 64); }
  bool useRe = (sre >= sim);
  double n = sqrt(useRe ? sre : sim);
  double inv = (n > 0.0) ? 1.0/n : 1.0;
  for (int p=t; p<sz; p+=64){
    double v = useRe ? Tre[off+p] : Tim[off+p];
    C3f[off+p] = (float)(v*inv);
  }
}

// ---------------------------------------------------------------------------
// W3t[c'][k], c' chunk-major: c' = chunk*64 + uv maps to original column
// ROFFT[lo][li] + uv*nlf + fi. 0.1 scale folded. Pitch 136, pad k>=100 = 0.
// ---------------------------------------------------------------------------
__global__ __launch_bounds__(256) void prep_w3t_kernel(const float* __restrict__ W3,
                                                       __hip_bfloat16* __restrict__ W3t){
  int idx = blockIdx.x*256 + threadIdx.x;
  if (idx >= 1216*136) return;
  int cp = idx/136, k = idx%136;
  int chunk = cp>>6, uv = cp&63;
  int lo = CB_LO[chunk], li = CB_LI[chunk], lf = CB_LF[chunk];
  int lmin = lo<li ? lo : li;
  int nlf = 2*lmin+1;
  int fi = lf - (lo>li ? lo-li : li-lo);
  int c = ROFFT[lo][li] + uv*nlf + fi;
  float v = (k < 100) ? 0.1f*W3[(size_t)k*NCOL + c] : 0.f;
  W3t[idx] = __float2bfloat16(v);
}

// ---------------------------------------------------------------------------
// Radial hidden chain -> h_bf[e][136] bf16 (weights straight from global).
// ---------------------------------------------------------------------------
__device__ __forceinline__ float swishf(float s){
  return SWISH_SCALE * s / (1.f + __expf(-s));
}

__global__ __launch_bounds__(256,3) void radial_hidden_kernel(
    const float* __restrict__ radii,
    const float* __restrict__ W0, const float* __restrict__ W1, const float* __restrict__ W2,
    __hip_bfloat16* __restrict__ h_bf, int E)
{
  __shared__ __align__(16) float sX[6400];   // [er][k] pitch 100; reused as bf16 staging
  __shared__ float sY[6400];
  __shared__ float sbas[640];
  const int t = threadIdx.x;
  const int et0 = blockIdx.x*64;

  for (int p=t; p<640; p+=256){
    int er = p/10, k = p%10;
    int eg = et0 + er;
    float r = (eg < E) ? radii[eg] : 0.f;
    float c = 0.7f + (2.5f/9.0f)*(float)k;
    float d = (r - c) * (9.0f/2.5f);
    sbas[p] = __expf(-d*d);
  }
  __syncthreads();
  for (int p=t; p<6400; p+=256){
    int er = p/100, o = p%100;
    float s = 0.f;
    #pragma unroll
    for (int k=0;k<10;++k) s += sbas[er*10+k]*W0[k*100+o];
    sX[p] = swishf(s*0.3162277660168379f);   // 1/sqrt(10)
  }
  __syncthreads();
  for (int q=t; q<400; q+=256){
    int erb = (q/25)*4, ob = (q%25)*4;
    float acc[4][4] = {};
    for (int k=0;k<100;++k){
      float4 w = *(const float4*)&W1[k*100+ob];
      #pragma unroll
      for (int i=0;i<4;++i){
        float a = sX[(erb+i)*100+k];
        acc[i][0]+=a*w.x; acc[i][1]+=a*w.y; acc[i][2]+=a*w.z; acc[i][3]+=a*w.w;
      }
    }
    #pragma unroll
    for (int i=0;i<4;++i){
      float4 v = make_float4(swishf(acc[i][0]*0.1f),swishf(acc[i][1]*0.1f),
                             swishf(acc[i][2]*0.1f),swishf(acc[i][3]*0.1f));
      *(float4*)&sY[(erb+i)*100+ob] = v;
    }
  }
  __syncthreads();

  __hip_bfloat16* sHB = (__hip_bfloat16*)sX;
  for (int p=t; p<64*36; p+=256){
    int er = p/36, k = 100 + p%36;
    sHB[er*136 + k] = __float2bfloat16(0.f);
  }
  for (int q=t; q<400; q+=256){
    int erb = (q/25)*4, ob = (q%25)*4;
    float acc[4][4] = {};
    for (int k=0;k<100;++k){
      float4 w = *(const float4*)&W2[k*100+ob];
      #pragma unroll
      for (int i=0;i<4;++i){
        float a = sY[(erb+i)*100+k];
        acc[i][0]+=a*w.x; acc[i][1]+=a*w.y; acc[i][2]+=a*w.z; acc[i][3]+=a*w.w;
      }
    }
    #pragma unroll
    for (int i=0;i<4;++i){
      __hip_bfloat16 hv[4];
      #pragma unroll
      for (int j=0;j<4;++j) hv[j] = __float2bfloat16(swishf(acc[i][j]*0.1f));
      *(short4*)&sHB[(erb+i)*136 + ob] = *(short4*)hv;
    }
  }
  __syncthreads();
  {
    const float4* sm = (const float4*)sHB;
    float4* gm = (float4*)(h_bf + (size_t)et0*136);
    for (int p=t; p<1088; p+=256) gm[p] = sm[p];
  }
}

// ---------------------------------------------------------------------------
// CSR of edges by target node
// ---------------------------------------------------------------------------
__global__ __launch_bounds__(256) void hist_kernel(const int* __restrict__ ei,
                                                   int* __restrict__ deg, int E){
  int e = blockIdx.x*256 + threadIdx.x;
  if (e < E) atomicAdd(&deg[ei[E+e]], 1);
}

__global__ __launch_bounds__(256) void scan_kernel(const int* __restrict__ deg,
                                                   int* __restrict__ off,
                                                   int* __restrict__ cursor, int N, int E){
  __shared__ int part[256], spref[256];
  const int t = threadIdx.x;
  const int CH = (N + 255)/256;
  int lo = t*CH, hi = lo+CH < N ? lo+CH : N;
  int s = 0;
  for (int n=lo; n<hi; ++n) s += deg[n];
  part[t] = s;
  __syncthreads();
  if (t == 0){
    int run = 0;
    for (int i=0;i<256;++i){ spref[i] = run; run += part[i]; }
  }
  __syncthreads();
  int run = spref[t];
  for (int n=lo; n<hi; ++n){ off[n] = run; cursor[n] = run; run += deg[n]; }
  if (t == 255) off[N] = E;
}

__global__ __launch_bounds__(256) void fill_kernel(const int* __restrict__ ei,
                                                   int* __restrict__ cursor,
                                                   int* __restrict__ eid, int E){
  int e = blockIdx.x*256 + threadIdx.x;
  if (e < E){
    int idx = atomicAdd(&cursor[ei[E+e]], 1);
    eid[idx] = e;
  }
}

// ---------------------------------------------------------------------------
// Gather: one 64-lane wave per node; writes every output element exactly once.
// ---------------------------------------------------------------------------
__global__ __launch_bounds__(64) void gather_kernel(const float* __restrict__ msg,
                                                    const int* __restrict__ off,
                                                    const int* __restrict__ eid,
                                                    float* __restrict__ out, int N){
  const int n = blockIdx.x;
  const int t = threadIdx.x;
  const int s = off[n], e1 = off[n+1];
  float a0 = 0.f, a1 = 0.f;
  for (int i=s; i<e1; ++i){
    const float* m = msg + (size_t)eid[i]*FEATD;
    a0 += m[t];
    if (t < 8) a1 += m[64+t];
  }
  out[(size_t)n*FEATD + t] = a0;
  if (t < 8) out[(size_t)n*FEATD + 64 + t] = a1;
}

// ---------------------------------------------------------------------------
// Fused GEMM+TP, barrier-free, H-trick consume, b128 LDS.
// 256 thr = 4 waves; 64 edges/block; wave owns edges [16wv,16wv+16);
// role r owns u-rows {2r,2r+1}.
// ---------------------------------------------------------------------------
constexpr int OF_RT  = 0;         // 64*68 f32 = 17408  ([e][68] row layout)
constexpr int OF_ACC = 17408;     // 64*72 f32 = 18432
constexpr int OF_F   = 35840;     // 64*76 f32 = 19456  (f32 F, pitch 76)
constexpr int OF_RSH = 55296;     // 64*25 f32 = 6400
constexpr int OF_KV  = 61696;     // 64*26 f32 = 6656
constexpr int OF_C3  = 68352;     // 1225 f32 = 4900
constexpr int OF_SRC = 73252;     // 64 int = 256
constexpr int SMEM_SZ = 73508;    // 73.5 KB -> 2 blocks/CU

template<int LO,int LI,int LF>
__device__ __forceinline__ void phase(
    int chunk, const __hip_bfloat16* __restrict__ W3t, const bf16x8 (&hf)[4],
    float* sRt, float* sFf, float* sRsh, float* sKV, const float* sC3,
    float* sAcc, int t)
{
  constexpr int NO = 2*LO+1, NI = 2*LI+1, NF = 2*LF+1;
  constexpr int C3B = C3OFFT[LO][LI][LF];
  constexpr int FO  = FOFFT[LI];

  const int e = t >> 2, role = t & 3;
  const int lane = t & 63, wv = t >> 6;
  const int lr = lane & 15, lq = lane >> 4;

  // ---- 1. kv[e][o*NI+mi] = sum_mf C3 * y : quad-split (wave-local) ----
  {
    float y[NF];
    #pragma unroll
    for (int mf=0; mf<NF; ++mf) y[mf] = sRsh[e*25 + LF*LF + mf];
    for (int it = role; it < NO*NI; it += 4){
      float s = 0.f;
      #pragma unroll
      for (int mf=0; mf<NF; ++mf) s += sC3[C3B + it*NF + mf] * y[mf];
      sKV[e*26 + it] = s;
    }
  }
  // ---- 2. MFMA: Rt[e][c], A straight from global; b128 LDS stores ----
  {
    const __hip_bfloat16* wb = W3t + (size_t)chunk*64*136;
    f32x4 a4[4] = {};
    #pragma unroll
    for (int ks=0; ks<4; ++ks){
      #pragma unroll
      for (int ct=0; ct<4; ++ct){
        bf16x8 a = *(const bf16x8*)&wb[(ct*16+lr)*136 + ks*32 + lq*8];
        a4[ct] = __builtin_amdgcn_mfma_f32_16x16x32_bf16(a, hf[ks], a4[ct], 0, 0, 0);
      }
    }
    // C frag: col(lr)=e within wave, rows ct*16+lq*4+r = c, r consecutive -> b128
    #pragma unroll
    for (int ct=0; ct<4; ++ct)
      *(f32x4*)&sRt[(wv*16 + lr)*68 + ct*16 + lq*4] = a4[ct];
  }
  __builtin_amdgcn_wave_barrier();   // pin LDS order (writes above, reads below)

  // ---- 3. consume (H-trick): H[du][mi] = sum_v R[u,v]*F[v,mi] ----
  {
    float H[2][NI];
    #pragma unroll
    for (int du=0; du<2; ++du)
      #pragma unroll
      for (int mi=0; mi<NI; ++mi) H[du][mi] = 0.f;

    #pragma unroll
    for (int vg=0; vg<2; ++vg){
      float fb[4*NI];
      #pragma unroll
      for (int p=0; p<NI; ++p)
        *(f32x4*)&fb[p*4] = *(const f32x4*)&sFf[e*76 + FO + vg*4*NI + p*4];
      #pragma unroll
      for (int du=0; du<2; ++du){
        const int u = role*2 + du;
        f32x4 rv = *(const f32x4*)&sRt[e*68 + u*8 + vg*4];
        #pragma unroll
        for (int v=0; v<4; ++v)
          #pragma unroll
          for (int mi=0; mi<NI; ++mi)
            H[du][mi] += rv[v] * fb[v*NI + mi];
      }
    }
    // s[o] = sum_mi kv[o,mi]*H[du][mi]; accumulate into sAcc (role-disjoint)
    const int u0 = role*2, u1 = role*2 + 1;
    const int b0 = e*72 + ((LO==0) ? u0 : (LO==1) ? 8 + u0*3 : 32 + u0*5);
    const int b1 = e*72 + ((LO==0) ? u1 : (LO==1) ? 8 + u1*3 : 32 + u1*5);
    #pragma unroll
    for (int o=0; o<NO; ++o){
      float s0 = 0.f, s1 = 0.f;
      #pragma unroll
      for (int mi=0; mi<NI; ++mi){
        float kvv = sKV[e*26 + o*NI + mi];
        s0 += kvv * H[0][mi];
        s1 += kvv * H[1][mi];
      }
      sAcc[b0 + o] += s0;
      sAcc[b1 + o] += s1;
    }
  }
  __builtin_amdgcn_wave_barrier();   // consume reads done before next phase writes
}

__global__ __launch_bounds__(256,2) void fused_kernel(
    const float* __restrict__ feats, const int* __restrict__ ei,
    const float* __restrict__ rsh, const __hip_bfloat16* __restrict__ h_bf,
    const __hip_bfloat16* __restrict__ W3t, const float* __restrict__ C3g,
    float* __restrict__ msg, int E)
{
  __shared__ __align__(16) char smem[SMEM_SZ];
  float* sRt  = (float*)(smem + OF_RT);
  float* sAcc = (float*)(smem + OF_ACC);
  float* sFf  = (float*)(smem + OF_F);
  float* sRsh = (float*)(smem + OF_RSH);
  float* sKV  = (float*)(smem + OF_KV);
  float* sC3  = (float*)(smem + OF_C3);
  int*   sSrc = (int*)(smem + OF_SRC);

  const int t = threadIdx.x;
  const int eb = blockIdx.x*64;

  // ---- h fragments into registers (B-operand, fixed across all 19 phases) ----
  bf16x8 hf[4];
  {
    const int lane = t & 63, wv = t >> 6;
    const int lr = lane & 15, lq = lane >> 4;
    const __hip_bfloat16* hrow = h_bf + (size_t)(eb + wv*16 + lr)*136;
    #pragma unroll
    for (int ks=0; ks<4; ++ks)
      hf[ks] = *(const bf16x8*)&hrow[ks*32 + lq*8];
  }
  // ---- prologue staging ----
  for (int p=t; p<4608; p+=256) sAcc[p] = 0.f;
  for (int p=t; p<64; p+=256){
    int e = eb + p;
    sSrc[p] = (e < E) ? ei[e] : 0;
  }
  for (int p=t; p<1600; p+=256){
    int el = p/25, j = p%25;
    int e = eb + el;
    sRsh[el*25 + j] = (e < E) ? rsh[(size_t)e*25 + j] : 0.f;
  }
  for (int p=t; p<C3TOT; p+=256) sC3[p] = C3g[p];
  __syncthreads();
  for (int p=t; p<64*72; p+=256){
    int el = p/72, j = p%72;
    sFf[el*76 + j] = feats[(size_t)sSrc[el]*72 + j];
  }
  __syncthreads();   // sFf visible; main loop below is barrier-free

  // ---- 19 phases, no __syncthreads ----
  phase<0,0,0>( 0, W3t, hf, sRt, sFf, sRsh, sKV, sC3, sAcc, t);
  phase<0,1,1>( 1, W3t, hf, sRt, sFf, sRsh, sKV, sC3, sAcc, t);
  phase<0,2,2>( 2, W3t, hf, sRt, sFf, sRsh, sKV, sC3, sAcc, t);
  phase<1,0,1>( 3, W3t, hf, sRt, sFf, sRsh, sKV, sC3, sAcc, t);
  phase<1,1,0>( 4, W3t, hf, sRt, sFf, sRsh, sKV, sC3, sAcc, t);
  phase<1,1,1>( 5, W3t, hf, sRt, sFf, sRsh, sKV, sC3, sAcc, t);
  phase<1,1,2>( 6, W3t, hf, sRt, sFf, sRsh, sKV, sC3, sAcc, t);
  phase<1,2,1>( 7, W3t, hf, sRt, sFf, sRsh, sKV, sC3, sAcc, t);
  phase<1,2,2>( 8, W3t, hf, sRt, sFf, sRsh, sKV, sC3, sAcc, t);
  phase<1,2,3>( 9, W3t, hf, sRt, sFf, sRsh, sKV, sC3, sAcc, t);
  phase<2,0,2>(10, W3t, hf, sRt, sFf, sRsh, sKV, sC3, sAcc, t);
  phase<2,1,1>(11, W3t, hf, sRt, sFf, sRsh, sKV, sC3, sAcc, t);
  phase<2,1,2>(12, W3t, hf, sRt, sFf, sRsh, sKV, sC3, sAcc, t);
  phase<2,1,3>(13, W3t, hf, sRt, sFf, sRsh, sKV, sC3, sAcc, t);
  phase<2,2,0>(14, W3t, hf, sRt, sFf, sRsh, sKV, sC3, sAcc, t);
  phase<2,2,1>(15, W3t, hf, sRt, sFf, sRsh, sKV, sC3, sAcc, t);
  phase<2,2,2>(16, W3t, hf, sRt, sFf, sRsh, sKV, sC3, sAcc, t);
  phase<2,2,3>(17, W3t, hf, sRt, sFf, sRsh, sKV, sC3, sAcc, t);
  phase<2,2,4>(18, W3t, hf, sRt, sFf, sRsh, sKV, sC3, sAcc, t);

  __syncthreads();   // sAcc complete across waves

  // ---- epilogue: normalize during coalesced float4 stream-out ----
  {
    const float4* sm = (const float4*)sAcc;
    float4* gm = (float4*)(msg + (size_t)eb*FEATD);
    for (int p=t; p<1152; p+=256){
      int j4 = p % 18;
      float n = (j4 < 2) ? 0.72360125f : (j4 < 8) ? 0.8204867f : 0.9341652f;
      float4 v = sm[p];
      v.x *= n; v.y *= n; v.z *= n; v.w *= n;
      gm[p] = v;
    }
  }
}

// ---------------------------------------------------------------------------
extern "C" void kernel_launch(void* const* d_in, const int* in_sizes, int n_in,
                              void* d_out, int out_size, void* d_ws, size_t ws_size,
                              hipStream_t stream)
{
  const float* feats = (const float*)d_in[0];
  const int*   ei    = (const int*)d_in[1];
  const float* radii = (const float*)d_in[2];
  const float* rsh   = (const float*)d_in[3];
  const float* W0    = (const float*)d_in[4];
  const float* W1    = (const float*)d_in[5];
  const float* W2    = (const float*)d_in[6];
  const float* W3    = (const float*)d_in[7];
  float* out = (float*)d_out;
  const int E = in_sizes[2];
  const int N = in_sizes[0]/FEATD;

  const int EPAD = ((E + 63)/64)*64;
  const int NBLK = EPAD/64;

  char* ws = (char*)d_ws;
  size_t off_b = 0;
  float*  C3f = (float*)(ws + off_b);  off_b += 8192;
  double* Tre = (double*)(ws + off_b); off_b += 12288;
  double* Tim = (double*)(ws + off_b); off_b += 12288;          // 32768
  __hip_bfloat16* W3t  = (__hip_bfloat16*)(ws + off_b); off_b += 335872;  // 368640
  __hip_bfloat16* h_bf = (__hip_bfloat16*)(ws + off_b); off_b += (size_t)EPAD*272;
  float* msg = (float*)(ws + off_b);   off_b += (size_t)EPAD*FEATD*4;
  int* deg    = (int*)(ws + off_b);    off_b += (size_t)N*4;
  int* offv   = (int*)(ws + off_b);    off_b += (size_t)(N+1)*4;
  int* cursor = (int*)(ws + off_b);    off_b += (size_t)N*4;
  int* eid    = (int*)(ws + off_b);    off_b += (size_t)E*4;

  // constants / tables
  c3_build_kernel<<<dim3((C3TOT+63)/64), dim3(64), 0, stream>>>(Tre, Tim);
  c3_norm_kernel<<<dim3(NCOMBO), dim3(64), 0, stream>>>(Tre, Tim, C3f);
  prep_w3t_kernel<<<dim3((1216*136+255)/256), dim3(256), 0, stream>>>(W3, W3t);

  // CSR of edges by target
  hipMemsetAsync(deg, 0, (size_t)N*4, stream);
  hist_kernel<<<dim3((E+255)/256), dim3(256), 0, stream>>>(ei, deg, E);
  scan_kernel<<<dim3(1), dim3(256), 0, stream>>>(deg, offv, cursor, N, E);
  fill_kernel<<<dim3((E+255)/256), dim3(256), 0, stream>>>(ei, cursor, eid, E);

  // main pipeline
  radial_hidden_kernel<<<dim3(NBLK), dim3(256), 0, stream>>>(radii, W0, W1, W2, h_bf, E);
  fused_kernel<<<dim3(NBLK), dim3(256), 0, stream>>>(feats, ei, rsh, h_bf, W3t, C3f, msg, E);
  gather_kernel<<<dim3(N), dim3(64), 0, stream>>>(msg, offv, eid, out, N);
}

// Round 14
// 425.835 us; speedup vs baseline: 2.4855x; 1.1379x over previous
//
#include <hip/hip_runtime.h>
#include <hip/hip_bf16.h>
#include <math.h>

// ============================================================================
// MinimalNetwork, round 14: r13 (MFMA radial) with the k-pad bug fixed.
// r13's NaN: layer-2 output pad only zeroed k=112..115,120..123 — 116..119 and
// 124..127 were uninitialized LDS, read by layer-3 MFMA (ks=3 covers k=96..127).
// Fix: 64 lanes = 16 rows x 4 short4-quarters zero k=112..127 completely.
//   radial_mfma  : layer1 (K=10) VALU -> bf16; layers 2,3 16x16x32 MFMA.
//   fused_kernel : unchanged (H-trick, b128, barrier-free, LDS accumulator).
// ============================================================================

#define FEATD 72
#define NCOL 1216
#define SWISH_SCALE 1.679177f

typedef __attribute__((ext_vector_type(8))) short bf16x8;
typedef __attribute__((ext_vector_type(4))) float f32x4;

// ---- 19 (lo,li,lf) chunks; CB_OFF = offsets into the C3 coefficient pool ----
constexpr int NCOMBO = 19;
constexpr int CB_LO[NCOMBO] = {0,0,0,1,1,1,1,1,1,1,2,2,2,2,2,2,2,2,2};
constexpr int CB_LI[NCOMBO] = {0,1,2,0,1,1,1,2,2,2,0,1,1,1,2,2,2,2,2};
constexpr int CB_LF[NCOMBO] = {0,1,2,1,0,1,2,1,2,3,2,1,2,3,0,1,2,3,4};
constexpr int CB_OFF[NCOMBO] = {0,1,10,35,44,53,80,125,170,245,350,375,420,495,600,625,700,825,1000};
constexpr int CB_SZ[NCOMBO]  = {1,9,25,9,9,27,45,45,75,105,25,45,75,105,25,75,125,175,225};
constexpr int C3TOT = 1225;

constexpr int C3OFFT[3][3][5] = {
  { {0,-1,-1,-1,-1}, {-1,1,-1,-1,-1}, {-1,-1,10,-1,-1} },
  { {-1,35,-1,-1,-1}, {44,53,80,-1,-1}, {-1,125,170,245,-1} },
  { {-1,-1,350,-1,-1}, {-1,375,420,495,-1}, {600,625,700,825,1000} }
};
constexpr int ROFFT[3][3] = {{0,64,128},{192,256,448},{640,704,896}};
constexpr int FOFFT[3]   = {0,8,32};

__device__ const double d_fact[11] = {1.,1.,2.,6.,24.,120.,720.,5040.,40320.,362880.,3628800.};

// ---------------------------------------------------------------------------
// Wigner 3j (complex basis, Racah) in double precision + real change of basis
// ---------------------------------------------------------------------------
__device__ double w3j_entry(int j1,int j2,int j3,int m1,int m2,int m3){
  if (m1+m2+m3 != 0) return 0.0;
  int dj = j1-j2; if (dj<0) dj=-dj;
  if (j3 < dj || j3 > j1+j2) return 0.0;
  int t1 = j2 - m1 - j3, t2 = j1 + m2 - j3;
  int kmin = 0; if (t1>kmin) kmin=t1; if (t2>kmin) kmin=t2;
  int kmax = j1+j2-j3; if (j1-m1<kmax) kmax=j1-m1; if (j2+m2<kmax) kmax=j2+m2;
  double s = 0.0;
  for (int k=kmin;k<=kmax;++k){
    double den = d_fact[k]*d_fact[k-t1]*d_fact[k-t2]*d_fact[j1+j2-j3-k]
               * d_fact[j1-m1-k]*d_fact[j2+m2-k];
    s += ((k&1)? -1.0:1.0)/den;
  }
  double pref = sqrt(d_fact[j1+j2-j3]*d_fact[j1-j2+j3]*d_fact[-j1+j2+j3]/d_fact[j1+j2+j3+1]
               * d_fact[j1+m1]*d_fact[j1-m1]*d_fact[j2+m2]*d_fact[j2-m2]
               * d_fact[j3+m3]*d_fact[j3-m3]);
  int ex = j1-j2-m3;
  if (ex & 1) pref = -pref;
  return pref*s;
}

__device__ void cob(int l, int r, int c, double& re, double& im){
  re = 0.0; im = 0.0;
  int mr = r - l, mc = c - l;
  const double s = 0.70710678118654752440;
  if (mr == 0) { if (mc == 0) re = 1.0; return; }
  if (mr > 0) {
    if (mc == mr)       re = (mr & 1) ? -s : s;
    else if (mc == -mr) re = s;
  } else {
    int m = -mr;
    if (mc == -m)      im = s;
    else if (mc == m)  im = (m & 1) ? s : -s;
  }
}

__global__ void c3_build_kernel(double* __restrict__ Tre, double* __restrict__ Tim){
  int idx = blockIdx.x*64 + threadIdx.x;
  if (idx >= C3TOT) return;
  int c = 0;
  while (c+1 < NCOMBO && idx >= CB_OFF[c+1]) ++c;
  int lo = CB_LO[c], li = CB_LI[c], lf = CB_LF[c];
  int n2 = 2*li+1, n3 = 2*lf+1;
  int loc = idx - CB_OFF[c];
  int a = loc/(n2*n3), b = (loc/n3)%n2, g = loc%n3;
  double sre=0.0, sim=0.0;
  for (int m1=-lo; m1<=lo; ++m1){
    for (int m2=-li; m2<=li; ++m2){
      int m3 = -m1-m2;
      if (m3 < -lf || m3 > lf) continue;
      double w = w3j_entry(lo,li,lf,m1,m2,m3);
      if (w == 0.0) continue;
      double r1,i1,r2,i2,r3,i3;
      cob(lo, a, m1+lo, r1,i1);
      cob(li, b, m2+li, r2,i2);
      cob(lf, g, m3+lf, r3,i3);
      double rr = r1*r2 - i1*i2, ri = r1*i2 + i1*r2;
      double fr = rr*r3 - ri*i3, fi = rr*i3 + ri*r3;
      sre += fr*w; sim += fi*w;
    }
  }
  Tre[idx] = sre; Tim[idx] = sim;
}

__global__ void c3_norm_kernel(const double* __restrict__ Tre, const double* __restrict__ Tim,
                               float* __restrict__ C3f){
  int c = blockIdx.x;
  int off = CB_OFF[c], sz = CB_SZ[c];
  int t = threadIdx.x;
  double sre=0.0, sim=0.0;
  for (int p=t; p<sz; p+=64){ double x=Tre[off+p], y=Tim[off+p]; sre+=x*x; sim+=y*y; }
  for (int m=1; m<64; m<<=1){ sre += __shfl_xor(sre, m, 64); sim += __shfl_xor(sim, m, 64); }
  bool useRe = (sre >= sim);
  double n = sqrt(useRe ? sre : sim);
  double inv = (n > 0.0) ? 1.0/n : 1.0;
  for (int p=t; p<sz; p+=64){
    double v = useRe ? Tre[off+p] : Tim[off+p];
    C3f[off+p] = (float)(v*inv);
  }
}

// ---------------------------------------------------------------------------
// W3t[c'][k] chunk-major (see r12). 0.1 scale folded. Pitch 136, pad zeroed.
// ---------------------------------------------------------------------------
__global__ __launch_bounds__(256) void prep_w3t_kernel(const float* __restrict__ W3,
                                                       __hip_bfloat16* __restrict__ W3t){
  int idx = blockIdx.x*256 + threadIdx.x;
  if (idx >= 1216*136) return;
  int cp = idx/136, k = idx%136;
  int chunk = cp>>6, uv = cp&63;
  int lo = CB_LO[chunk], li = CB_LI[chunk], lf = CB_LF[chunk];
  int lmin = lo<li ? lo : li;
  int nlf = 2*lmin+1;
  int fi = lf - (lo>li ? lo-li : li-lo);
  int c = ROFFT[lo][li] + uv*nlf + fi;
  float v = (k < 100) ? 0.1f*W3[(size_t)k*NCOL + c] : 0.f;
  W3t[idx] = __float2bfloat16(v);
}

// Wt[o][k] = bf16(0.1*W[k][o]), o<112 (rows 100..111 zero), k<136 (k>=100 zero)
__global__ __launch_bounds__(256) void prep_wt_kernel(const float* __restrict__ W,
                                                      __hip_bfloat16* __restrict__ Wt){
  int idx = blockIdx.x*256 + threadIdx.x;
  if (idx >= 112*136) return;
  int o = idx/136, k = idx%136;
  float v = (o < 100 && k < 100) ? 0.1f*W[k*100+o] : 0.f;
  Wt[idx] = __float2bfloat16(v);
}

// ---------------------------------------------------------------------------
// Radial MLP with MFMA layers 2,3. 64 edges/block, 4 waves, 4 blocks/CU.
// ---------------------------------------------------------------------------
__device__ __forceinline__ float swishf(float s){
  return SWISH_SCALE * s / (1.f + __expf(-s));
}

__device__ __forceinline__ void radial_layer_mfma(
    const __hip_bfloat16* __restrict__ sIn,   // [64][136] bf16, rows e
    const __hip_bfloat16* __restrict__ Wt,    // [112][136] bf16 global
    __hip_bfloat16* __restrict__ sOut,        // [64][136] bf16
    int wv, int lr, int lq)
{
  bf16x8 bf[4];
  #pragma unroll
  for (int ks=0; ks<4; ++ks)
    bf[ks] = *(const bf16x8*)&sIn[(wv*16+lr)*136 + ks*32 + lq*8];
  f32x4 acc[7] = {};
  #pragma unroll
  for (int ks=0; ks<4; ++ks)
    #pragma unroll
    for (int ot=0; ot<7; ++ot){
      bf16x8 a = *(const bf16x8*)&Wt[(ot*16+lr)*136 + ks*32 + lq*8];
      acc[ot] = __builtin_amdgcn_mfma_f32_16x16x32_bf16(a, bf[ks], acc[ot], 0, 0, 0);
    }
  // C frag: col(lr)=e within wave, row(ot*16+lq*4+r)=o.  swish + bf16 + short4.
  #pragma unroll
  for (int ot=0; ot<7; ++ot){
    __hip_bfloat16 hv[4];
    #pragma unroll
    for (int r=0; r<4; ++r)
      hv[r] = __float2bfloat16(swishf(acc[ot][r]));   // Wt rows o>=100 zero -> swish(0)=0
    *(short4*)&sOut[(wv*16+lr)*136 + ot*16 + lq*4] = *(short4*)hv;
  }
  // zero o/k = 112..127 of own rows COMPLETELY: 64 lanes = 16 rows x 4 quarters
  {
    int lane = lq*16 + lr;            // 0..63
    int row = lane & 15, q = lane >> 4;   // q in 0..3
    short4 z = {0,0,0,0};
    *(short4*)&sOut[(wv*16+row)*136 + 112 + q*4] = z;
  }
}

__global__ __launch_bounds__(256,4) void radial_mfma_kernel(
    const float* __restrict__ radii, const float* __restrict__ W0,
    const __hip_bfloat16* __restrict__ W1t, const __hip_bfloat16* __restrict__ W2t,
    __hip_bfloat16* __restrict__ h_bf, int E)
{
  __shared__ float sbas[640];
  __shared__ __align__(16) __hip_bfloat16 sA[64*136];  // h1, then h3
  __shared__ __align__(16) __hip_bfloat16 sB[64*136];  // h2
  const int t = threadIdx.x;
  const int et0 = blockIdx.x*64;

  for (int p=t; p<640; p+=256){
    int er = p/10, k = p%10;
    int eg = et0 + er;
    float r = (eg < E) ? radii[eg] : 0.f;
    float c = 0.7f + (2.5f/9.0f)*(float)k;
    float d = (r - c) * (9.0f/2.5f);
    sbas[p] = __expf(-d*d);
  }
  __syncthreads();
  // layer 1 (K=10, VALU), h1 bf16 into sA; zero k-pad 100..135
  for (int p=t; p<6400; p+=256){
    int er = p/100, o = p%100;
    float s = 0.f;
    #pragma unroll
    for (int k=0;k<10;++k) s += sbas[er*10+k]*W0[k*100+o];
    sA[er*136+o] = __float2bfloat16(swishf(s*0.3162277660168379f));   // 1/sqrt(10)
  }
  for (int p=t; p<64*36; p+=256){
    int er = p/36, k = 100 + p%36;
    sA[er*136+k] = __float2bfloat16(0.f);
  }
  __syncthreads();   // everything below is wave-local (own 16 edge rows)

  const int lane = t & 63, wv = t >> 6;
  const int lr = lane & 15, lq = lane >> 4;

  radial_layer_mfma(sA, W1t, sB, wv, lr, lq);   // h2 = swish(0.1*h1@W1)
  __builtin_amdgcn_wave_barrier();
  radial_layer_mfma(sB, W2t, sA, wv, lr, lq);   // h3 = swish(0.1*h2@W2)
  __builtin_amdgcn_wave_barrier();
  // copy own 16 rows (16*136 bf16 = 272 float4) to global
  {
    const float4* sm = (const float4*)(sA + (size_t)(wv*16)*136);
    float4* gm = (float4*)(h_bf + (size_t)(et0 + wv*16)*136);
    for (int p=lane; p<272; p+=64) gm[p] = sm[p];
  }
}

// ---------------------------------------------------------------------------
// CSR of edges by target node
// ---------------------------------------------------------------------------
__global__ __launch_bounds__(256) void hist_kernel(const int* __restrict__ ei,
                                                   int* __restrict__ deg, int E){
  int e = blockIdx.x*256 + threadIdx.x;
  if (e < E) atomicAdd(&deg[ei[E+e]], 1);
}

__global__ __launch_bounds__(256) void scan_kernel(const int* __restrict__ deg,
                                                   int* __restrict__ off,
                                                   int* __restrict__ cursor, int N, int E){
  __shared__ int part[256], spref[256];
  const int t = threadIdx.x;
  const int CH = (N + 255)/256;
  int lo = t*CH, hi = lo+CH < N ? lo+CH : N;
  int s = 0;
  for (int n=lo; n<hi; ++n) s += deg[n];
  part[t] = s;
  __syncthreads();
  if (t == 0){
    int run = 0;
    for (int i=0;i<256;++i){ spref[i] = run; run += part[i]; }
  }
  __syncthreads();
  int run = spref[t];
  for (int n=lo; n<hi; ++n){ off[n] = run; cursor[n] = run; run += deg[n]; }
  if (t == 255) off[N] = E;
}

__global__ __launch_bounds__(256) void fill_kernel(const int* __restrict__ ei,
                                                   int* __restrict__ cursor,
                                                   int* __restrict__ eid, int E){
  int e = blockIdx.x*256 + threadIdx.x;
  if (e < E){
    int idx = atomicAdd(&cursor[ei[E+e]], 1);
    eid[idx] = e;
  }
}

// ---------------------------------------------------------------------------
// Gather: one 64-lane wave per node; writes every output element exactly once.
// ---------------------------------------------------------------------------
__global__ __launch_bounds__(64) void gather_kernel(const float* __restrict__ msg,
                                                    const int* __restrict__ off,
                                                    const int* __restrict__ eid,
                                                    float* __restrict__ out, int N){
  const int n = blockIdx.x;
  const int t = threadIdx.x;
  const int s = off[n], e1 = off[n+1];
  float a0 = 0.f, a1 = 0.f;
  for (int i=s; i<e1; ++i){
    const float* m = msg + (size_t)eid[i]*FEATD;
    a0 += m[t];
    if (t < 8) a1 += m[64+t];
  }
  out[(size_t)n*FEATD + t] = a0;
  if (t < 8) out[(size_t)n*FEATD + 64 + t] = a1;
}

// ---------------------------------------------------------------------------
// Fused GEMM+TP (unchanged from r12): barrier-free, H-trick, b128 LDS.
// ---------------------------------------------------------------------------
constexpr int OF_RT  = 0;         // 64*68 f32 = 17408  ([e][68] row layout)
constexpr int OF_ACC = 17408;     // 64*72 f32 = 18432
constexpr int OF_F   = 35840;     // 64*76 f32 = 19456
constexpr int OF_RSH = 55296;     // 64*25 f32 = 6400
constexpr int OF_KV  = 61696;     // 64*26 f32 = 6656
constexpr int OF_C3  = 68352;     // 1225 f32 = 4900
constexpr int OF_SRC = 73252;     // 64 int = 256
constexpr int SMEM_SZ = 73508;    // 73.5 KB -> 2 blocks/CU

template<int LO,int LI,int LF>
__device__ __forceinline__ void phase(
    int chunk, const __hip_bfloat16* __restrict__ W3t, const bf16x8 (&hf)[4],
    float* sRt, float* sFf, float* sRsh, float* sKV, const float* sC3,
    float* sAcc, int t)
{
  constexpr int NO = 2*LO+1, NI = 2*LI+1, NF = 2*LF+1;
  constexpr int C3B = C3OFFT[LO][LI][LF];
  constexpr int FO  = FOFFT[LI];

  const int e = t >> 2, role = t & 3;
  const int lane = t & 63, wv = t >> 6;
  const int lr = lane & 15, lq = lane >> 4;

  // ---- 1. kv[e][o*NI+mi] = sum_mf C3 * y : quad-split (wave-local) ----
  {
    float y[NF];
    #pragma unroll
    for (int mf=0; mf<NF; ++mf) y[mf] = sRsh[e*25 + LF*LF + mf];
    for (int it = role; it < NO*NI; it += 4){
      float s = 0.f;
      #pragma unroll
      for (int mf=0; mf<NF; ++mf) s += sC3[C3B + it*NF + mf] * y[mf];
      sKV[e*26 + it] = s;
    }
  }
  // ---- 2. MFMA: Rt[e][c], A straight from global; b128 LDS stores ----
  {
    const __hip_bfloat16* wb = W3t + (size_t)chunk*64*136;
    f32x4 a4[4] = {};
    #pragma unroll
    for (int ks=0; ks<4; ++ks){
      #pragma unroll
      for (int ct=0; ct<4; ++ct){
        bf16x8 a = *(const bf16x8*)&wb[(ct*16+lr)*136 + ks*32 + lq*8];
        a4[ct] = __builtin_amdgcn_mfma_f32_16x16x32_bf16(a, hf[ks], a4[ct], 0, 0, 0);
      }
    }
    #pragma unroll
    for (int ct=0; ct<4; ++ct)
      *(f32x4*)&sRt[(wv*16 + lr)*68 + ct*16 + lq*4] = a4[ct];
  }
  __builtin_amdgcn_wave_barrier();

  // ---- 3. consume (H-trick): H[du][mi] = sum_v R[u,v]*F[v,mi] ----
  {
    float H[2][NI];
    #pragma unroll
    for (int du=0; du<2; ++du)
      #pragma unroll
      for (int mi=0; mi<NI; ++mi) H[du][mi] = 0.f;

    #pragma unroll
    for (int vg=0; vg<2; ++vg){
      float fb[4*NI];
      #pragma unroll
      for (int p=0; p<NI; ++p)
        *(f32x4*)&fb[p*4] = *(const f32x4*)&sFf[e*76 + FO + vg*4*NI + p*4];
      #pragma unroll
      for (int du=0; du<2; ++du){
        const int u = role*2 + du;
        f32x4 rv = *(const f32x4*)&sRt[e*68 + u*8 + vg*4];
        #pragma unroll
        for (int v=0; v<4; ++v)
          #pragma unroll
          for (int mi=0; mi<NI; ++mi)
            H[du][mi] += rv[v] * fb[v*NI + mi];
      }
    }
    const int u0 = role*2, u1 = role*2 + 1;
    const int b0 = e*72 + ((LO==0) ? u0 : (LO==1) ? 8 + u0*3 : 32 + u0*5);
    const int b1 = e*72 + ((LO==0) ? u1 : (LO==1) ? 8 + u1*3 : 32 + u1*5);
    #pragma unroll
    for (int o=0; o<NO; ++o){
      float s0 = 0.f, s1 = 0.f;
      #pragma unroll
      for (int mi=0; mi<NI; ++mi){
        float kvv = sKV[e*26 + o*NI + mi];
        s0 += kvv * H[0][mi];
        s1 += kvv * H[1][mi];
      }
      sAcc[b0 + o] += s0;
      sAcc[b1 + o] += s1;
    }
  }
  __builtin_amdgcn_wave_barrier();
}

__global__ __launch_bounds__(256,2) void fused_kernel(
    const float* __restrict__ feats, const int* __restrict__ ei,
    const float* __restrict__ rsh, const __hip_bfloat16* __restrict__ h_bf,
    const __hip_bfloat16* __restrict__ W3t, const float* __restrict__ C3g,
    float* __restrict__ msg, int E)
{
  __shared__ __align__(16) char smem[SMEM_SZ];
  float* sRt  = (float*)(smem + OF_RT);
  float* sAcc = (float*)(smem + OF_ACC);
  float* sFf  = (float*)(smem + OF_F);
  float* sRsh = (float*)(smem + OF_RSH);
  float* sKV  = (float*)(smem + OF_KV);
  float* sC3  = (float*)(smem + OF_C3);
  int*   sSrc = (int*)(smem + OF_SRC);

  const int t = threadIdx.x;
  const int eb = blockIdx.x*64;

  bf16x8 hf[4];
  {
    const int lane = t & 63, wv = t >> 6;
    const int lr = lane & 15, lq = lane >> 4;
    const __hip_bfloat16* hrow = h_bf + (size_t)(eb + wv*16 + lr)*136;
    #pragma unroll
    for (int ks=0; ks<4; ++ks)
      hf[ks] = *(const bf16x8*)&hrow[ks*32 + lq*8];
  }
  for (int p=t; p<4608; p+=256) sAcc[p] = 0.f;
  for (int p=t; p<64; p+=256){
    int e = eb + p;
    sSrc[p] = (e < E) ? ei[e] : 0;
  }
  for (int p=t; p<1600; p+=256){
    int el = p/25, j = p%25;
    int e = eb + el;
    sRsh[el*25 + j] = (e < E) ? rsh[(size_t)e*25 + j] : 0.f;
  }
  for (int p=t; p<C3TOT; p+=256) sC3[p] = C3g[p];
  __syncthreads();
  for (int p=t; p<64*72; p+=256){
    int el = p/72, j = p%72;
    sFf[el*76 + j] = feats[(size_t)sSrc[el]*72 + j];
  }
  __syncthreads();

  phase<0,0,0>( 0, W3t, hf, sRt, sFf, sRsh, sKV, sC3, sAcc, t);
  phase<0,1,1>( 1, W3t, hf, sRt, sFf, sRsh, sKV, sC3, sAcc, t);
  phase<0,2,2>( 2, W3t, hf, sRt, sFf, sRsh, sKV, sC3, sAcc, t);
  phase<1,0,1>( 3, W3t, hf, sRt, sFf, sRsh, sKV, sC3, sAcc, t);
  phase<1,1,0>( 4, W3t, hf, sRt, sFf, sRsh, sKV, sC3, sAcc, t);
  phase<1,1,1>( 5, W3t, hf, sRt, sFf, sRsh, sKV, sC3, sAcc, t);
  phase<1,1,2>( 6, W3t, hf, sRt, sFf, sRsh, sKV, sC3, sAcc, t);
  phase<1,2,1>( 7, W3t, hf, sRt, sFf, sRsh, sKV, sC3, sAcc, t);
  phase<1,2,2>( 8, W3t, hf, sRt, sFf, sRsh, sKV, sC3, sAcc, t);
  phase<1,2,3>( 9, W3t, hf, sRt, sFf, sRsh, sKV, sC3, sAcc, t);
  phase<2,0,2>(10, W3t, hf, sRt, sFf, sRsh, sKV, sC3, sAcc, t);
  phase<2,1,1>(11, W3t, hf, sRt, sFf, sRsh, sKV, sC3, sAcc, t);
  phase<2,1,2>(12, W3t, hf, sRt, sFf, sRsh, sKV, sC3, sAcc, t);
  phase<2,1,3>(13, W3t, hf, sRt, sFf, sRsh, sKV, sC3, sAcc, t);
  phase<2,2,0>(14, W3t, hf, sRt, sFf, sRsh, sKV, sC3, sAcc, t);
  phase<2,2,1>(15, W3t, hf, sRt, sFf, sRsh, sKV, sC3, sAcc, t);
  phase<2,2,2>(16, W3t, hf, sRt, sFf, sRsh, sKV, sC3, sAcc, t);
  phase<2,2,3>(17, W3t, hf, sRt, sFf, sRsh, sKV, sC3, sAcc, t);
  phase<2,2,4>(18, W3t, hf, sRt, sFf, sRsh, sKV, sC3, sAcc, t);

  __syncthreads();

  {
    const float4* sm = (const float4*)sAcc;
    float4* gm = (float4*)(msg + (size_t)eb*FEATD);
    for (int p=t; p<1152; p+=256){
      int j4 = p % 18;
      float n = (j4 < 2) ? 0.72360125f : (j4 < 8) ? 0.8204867f : 0.9341652f;
      float4 v = sm[p];
      v.x *= n; v.y *= n; v.z *= n; v.w *= n;
      gm[p] = v;
    }
  }
}

// ---------------------------------------------------------------------------
extern "C" void kernel_launch(void* const* d_in, const int* in_sizes, int n_in,
                              void* d_out, int out_size, void* d_ws, size_t ws_size,
                              hipStream_t stream)
{
  const float* feats = (const float*)d_in[0];
  const int*   ei    = (const int*)d_in[1];
  const float* radii = (const float*)d_in[2];
  const float* rsh   = (const float*)d_in[3];
  const float* W0    = (const float*)d_in[4];
  const float* W1    = (const float*)d_in[5];
  const float* W2    = (const float*)d_in[6];
  const float* W3    = (const float*)d_in[7];
  float* out = (float*)d_out;
  const int E = in_sizes[2];
  const int N = in_sizes[0]/FEATD;

  const int EPAD = ((E + 63)/64)*64;
  const int NBLK = EPAD/64;

  char* ws = (char*)d_ws;
  size_t off_b = 0;
  float*  C3f = (float*)(ws + off_b);  off_b += 8192;
  double* Tre = (double*)(ws + off_b); off_b += 12288;
  double* Tim = (double*)(ws + off_b); off_b += 12288;          // 32768
  __hip_bfloat16* W3t = (__hip_bfloat16*)(ws + off_b); off_b += 335872;
  __hip_bfloat16* W1t = (__hip_bfloat16*)(ws + off_b); off_b += 30720;   // 112*136 bf16
  __hip_bfloat16* W2t = (__hip_bfloat16*)(ws + off_b); off_b += 30720;
  __hip_bfloat16* h_bf = (__hip_bfloat16*)(ws + off_b); off_b += (size_t)EPAD*272;
  float* msg = (float*)(ws + off_b);   off_b += (size_t)EPAD*FEATD*4;
  int* deg    = (int*)(ws + off_b);    off_b += (size_t)N*4;
  int* offv   = (int*)(ws + off_b);    off_b += (size_t)(N+1)*4;
  int* cursor = (int*)(ws + off_b);    off_b += (size_t)N*4;
  int* eid    = (int*)(ws + off_b);    off_b += (size_t)E*4;

  // constants / tables
  c3_build_kernel<<<dim3((C3TOT+63)/64), dim3(64), 0, stream>>>(Tre, Tim);
  c3_norm_kernel<<<dim3(NCOMBO), dim3(64), 0, stream>>>(Tre, Tim, C3f);
  prep_w3t_kernel<<<dim3((1216*136+255)/256), dim3(256), 0, stream>>>(W3, W3t);
  prep_wt_kernel<<<dim3((112*136+255)/256), dim3(256), 0, stream>>>(W1, W1t);
  prep_wt_kernel<<<dim3((112*136+255)/256), dim3(256), 0, stream>>>(W2, W2t);

  // CSR of edges by target
  hipMemsetAsync(deg, 0, (size_t)N*4, stream);
  hist_kernel<<<dim3((E+255)/256), dim3(256), 0, stream>>>(ei, deg, E);
  scan_kernel<<<dim3(1), dim3(256), 0, stream>>>(deg, offv, cursor, N, E);
  fill_kernel<<<dim3((E+255)/256), dim3(256), 0, stream>>>(ei, cursor, eid, E);

  // main pipeline
  radial_mfma_kernel<<<dim3(NBLK), dim3(256), 0, stream>>>(radii, W0, W1t, W2t, h_bf, E);
  fused_kernel<<<dim3(NBLK), dim3(256), 0, stream>>>(feats, ei, rsh, h_bf, W3t, C3f, msg, E);
  gather_kernel<<<dim3(N), dim3(64), 0, stream>>>(msg, offv, eid, out, N);
}